// Round 1
// baseline (1890.216 us; speedup 1.0000x reference)
//
#include <hip/hip_runtime.h>

#define NN 100000
#define NE 1600000
#define DIN 8
#define DH 32
#define NACT 3

// ---------------- degree ----------------
__global__ void deg_kernel(const int* __restrict__ dst, float* __restrict__ deg) {
    int e = blockIdx.x * blockDim.x + threadIdx.x;
    if (e < NE) atomicAdd(&deg[dst[e]], 1.0f);
}

// ---------------- scatter d=8 (layer 1 input) ----------------
// one thread per (edge, half-row of 4): idx in [0, 2E)
__global__ void scatter8(const float* __restrict__ x, const int* __restrict__ src,
                         const int* __restrict__ dst, float* __restrict__ msg) {
    int idx = blockIdx.x * blockDim.x + threadIdx.x;
    if (idx >= NE * 2) return;
    int e = idx >> 1;
    int c = (idx & 1) * 4;
    int s = src[e], d = dst[e];
    float4 v = *reinterpret_cast<const float4*>(&x[s * DIN + c]);
    float* p = &msg[d * DIN + c];
    atomicAdd(p + 0, v.x);
    atomicAdd(p + 1, v.y);
    atomicAdd(p + 2, v.z);
    atomicAdd(p + 3, v.w);
}

// ---------------- scatter d=32 ----------------
// one thread per (edge, quarter of 4 floats): idx in [0, 8E)
__global__ void scatter32(const float* __restrict__ h, const int* __restrict__ src,
                          const int* __restrict__ dst, float* __restrict__ msg) {
    int idx = blockIdx.x * blockDim.x + threadIdx.x;
    if (idx >= NE * 8) return;
    int e = idx >> 3;
    int c = (idx & 7) * 4;
    int s = src[e], d = dst[e];
    float4 v = *reinterpret_cast<const float4*>(&h[s * DH + c]);
    float* p = &msg[d * DH + c];
    atomicAdd(p + 0, v.x);
    atomicAdd(p + 1, v.y);
    atomicAdd(p + 2, v.z);
    atomicAdd(p + 3, v.w);
}

// ---------------- node update, din=8 ----------------
// block = 256 = 8 nodes x 32 channels
__launch_bounds__(256)
__global__ void node8(const float* __restrict__ x, const float* __restrict__ msg,
                      const float* __restrict__ deg,
                      const float* __restrict__ Wl, const float* __restrict__ bl,
                      const float* __restrict__ Wr, float* __restrict__ hout) {
    __shared__ float sWl[DIN * DH];
    __shared__ float sWr[DIN * DH];
    __shared__ float sbl[DH];
    __shared__ float sme[8][DIN + 1];
    __shared__ float sxi[8][DIN + 1];

    int tid = threadIdx.x;
    if (tid < DIN * DH) { sWl[tid] = Wl[tid]; sWr[tid] = Wr[tid]; }
    if (tid < DH) sbl[tid] = bl[tid];

    int base = blockIdx.x * 8;
    if (tid < 64) {
        int n = tid >> 3, k = tid & 7;
        int node = base + n;
        if (node < NN) {
            float dg = fmaxf(deg[node], 1.0f);
            sme[n][k] = msg[node * DIN + k] / dg;
            sxi[n][k] = x[node * DIN + k];
        }
    }
    __syncthreads();

    int n = tid >> 5, j = tid & 31;
    int node = base + n;
    if (node >= NN) return;
    float acc = sbl[j];
#pragma unroll
    for (int k = 0; k < DIN; ++k)
        acc += sme[n][k] * sWl[k * DH + j] + sxi[n][k] * sWr[k * DH + j];
    hout[node * DH + j] = fmaxf(acc, 0.0f);
}

// ---------------- node update, din=32 ----------------
__launch_bounds__(256)
__global__ void node32(const float* __restrict__ hin, const float* __restrict__ msg,
                       const float* __restrict__ deg,
                       const float* __restrict__ Wl, const float* __restrict__ bl,
                       const float* __restrict__ Wr, float* __restrict__ hout) {
    __shared__ float sWl[DH * DH];
    __shared__ float sWr[DH * DH];
    __shared__ float sbl[DH];
    __shared__ float sme[8][DH + 1];
    __shared__ float sxi[8][DH + 1];

    int tid = threadIdx.x;
#pragma unroll
    for (int i = 0; i < 4; ++i) {
        sWl[tid + 256 * i] = Wl[tid + 256 * i];
        sWr[tid + 256 * i] = Wr[tid + 256 * i];
    }
    if (tid < DH) sbl[tid] = bl[tid];

    int base = blockIdx.x * 8;
    {
        int n = tid >> 5, k = tid & 31;
        int node = base + n;
        if (node < NN) {
            float dg = fmaxf(deg[node], 1.0f);
            sme[n][k] = msg[node * DH + k] / dg;
            sxi[n][k] = hin[node * DH + k];
        }
    }
    __syncthreads();

    int n = tid >> 5, j = tid & 31;
    int node = base + n;
    if (node >= NN) return;
    float acc = sbl[j];
#pragma unroll
    for (int k = 0; k < DH; ++k)
        acc += sme[n][k] * sWl[k * DH + j] + sxi[n][k] * sWr[k * DH + j];
    hout[node * DH + j] = fmaxf(acc, 0.0f);
}

// ---------------- layer-3 node update fused with MLP head ----------------
__launch_bounds__(256)
__global__ void node32_head(const float* __restrict__ hin, const float* __restrict__ msg,
                            const float* __restrict__ deg,
                            const float* __restrict__ Wl, const float* __restrict__ bl,
                            const float* __restrict__ Wr,
                            const float* __restrict__ Wh1, const float* __restrict__ bh1,
                            const float* __restrict__ Wh2, const float* __restrict__ bh2,
                            float* __restrict__ out) {
    __shared__ float sWl[DH * DH];
    __shared__ float sWr[DH * DH];
    __shared__ float sWh1[DH * DH];
    __shared__ float sWh2[DH * NACT];
    __shared__ float sbl[DH];
    __shared__ float sbh1[DH];
    __shared__ float sbh2[NACT];
    __shared__ float sme[8][DH + 1];
    __shared__ float sxi[8][DH + 1];
    __shared__ float sh3[8][DH + 1];
    __shared__ float shh[8][DH + 1];

    int tid = threadIdx.x;
#pragma unroll
    for (int i = 0; i < 4; ++i) {
        sWl[tid + 256 * i] = Wl[tid + 256 * i];
        sWr[tid + 256 * i] = Wr[tid + 256 * i];
        sWh1[tid + 256 * i] = Wh1[tid + 256 * i];
    }
    if (tid < DH * NACT) sWh2[tid] = Wh2[tid];
    if (tid < DH) { sbl[tid] = bl[tid]; sbh1[tid] = bh1[tid]; }
    if (tid < NACT) sbh2[tid] = bh2[tid];

    int base = blockIdx.x * 8;
    int n = tid >> 5, j = tid & 31;
    int node = base + n;
    {
        if (node < NN) {
            float dg = fmaxf(deg[node], 1.0f);
            sme[n][j] = msg[node * DH + j] / dg;
            sxi[n][j] = hin[node * DH + j];
        }
    }
    __syncthreads();

    bool live = (node < NN);
    float acc = sbl[j];
#pragma unroll
    for (int k = 0; k < DH; ++k)
        acc += sme[n][k] * sWl[k * DH + j] + sxi[n][k] * sWr[k * DH + j];
    if (live) sh3[n][j] = fmaxf(acc, 0.0f);
    __syncthreads();

    float acc2 = sbh1[j];
#pragma unroll
    for (int k = 0; k < DH; ++k)
        acc2 += sh3[n][k] * sWh1[k * DH + j];
    if (live) shh[n][j] = fmaxf(acc2, 0.0f);
    __syncthreads();

    if (live && j < NACT) {
        float o = sbh2[j];
#pragma unroll
        for (int k = 0; k < DH; ++k)
            o += shh[n][k] * sWh2[k * NACT + j];
        out[node * NACT + j] = o;
    }
}

extern "C" void kernel_launch(void* const* d_in, const int* in_sizes, int n_in,
                              void* d_out, int out_size, void* d_ws, size_t ws_size,
                              hipStream_t stream) {
    const float* x   = (const float*)d_in[0];
    const int*   ei  = (const int*)d_in[1];
    const int*   src = ei;
    const int*   dst = ei + NE;
    const float* Wl1 = (const float*)d_in[2];
    const float* bl1 = (const float*)d_in[3];
    const float* Wr1 = (const float*)d_in[4];
    const float* Wl2 = (const float*)d_in[5];
    const float* bl2 = (const float*)d_in[6];
    const float* Wr2 = (const float*)d_in[7];
    const float* Wl3 = (const float*)d_in[8];
    const float* bl3 = (const float*)d_in[9];
    const float* Wr3 = (const float*)d_in[10];
    const float* Wh1 = (const float*)d_in[11];
    const float* bh1 = (const float*)d_in[12];
    const float* Wh2 = (const float*)d_in[13];
    const float* bh2 = (const float*)d_in[14];
    float* out = (float*)d_out;

    float* ws  = (float*)d_ws;
    float* deg = ws;                       // N
    float* msg = ws + NN;                  // 32N (layer1 uses first 8N)
    float* hA  = ws + NN + 32 * NN;        // 32N
    float* hB  = ws + NN + 64 * NN;        // 32N

    hipMemsetAsync(deg, 0, NN * sizeof(float), stream);
    hipMemsetAsync(msg, 0, NN * DH * sizeof(float), stream);

    deg_kernel<<<(NE + 255) / 256, 256, 0, stream>>>(dst, deg);

    // ---- layer 1 ----
    scatter8<<<(NE * 2) / 256, 256, 0, stream>>>(x, src, dst, msg);
    node8<<<NN / 8, 256, 0, stream>>>(x, msg, deg, Wl1, bl1, Wr1, hA);

    // ---- layer 2 ----
    hipMemsetAsync(msg, 0, NN * DH * sizeof(float), stream);
    scatter32<<<(NE * 8) / 256, 256, 0, stream>>>(hA, src, dst, msg);
    node32<<<NN / 8, 256, 0, stream>>>(hA, msg, deg, Wl2, bl2, Wr2, hB);

    // ---- layer 3 + head ----
    hipMemsetAsync(msg, 0, NN * DH * sizeof(float), stream);
    scatter32<<<(NE * 8) / 256, 256, 0, stream>>>(hB, src, dst, msg);
    node32_head<<<NN / 8, 256, 0, stream>>>(hB, msg, deg, Wl3, bl3, Wr3,
                                            Wh1, bh1, Wh2, bh2, out);
}

// Round 2
// 475.352 us; speedup vs baseline: 3.9765x; 3.9765x over previous
//
#include <hip/hip_runtime.h>

#define NN 100000
#define NE 1600000
#define DIN 8
#define DH 32
#define NACT 3
#define NBLK 391          // ceil(NN/256)
#define PADN (NBLK * 256) // 100096

// ---------------- degree count (int) ----------------
__global__ void count_deg(const int* __restrict__ dst, int* __restrict__ degI) {
    int e = blockIdx.x * blockDim.x + threadIdx.x;
    if (e < NE) atomicAdd(&degI[dst[e]], 1);
}

// ---------------- scan step A: per-block inclusive scan ----------------
__launch_bounds__(256)
__global__ void scanA(const int* __restrict__ degI, int* __restrict__ incl,
                      int* __restrict__ bsum) {
    __shared__ int s[256];
    int i = blockIdx.x * 256 + threadIdx.x;
    int v = (i < NN) ? degI[i] : 0;
    s[threadIdx.x] = v;
    __syncthreads();
#pragma unroll
    for (int off = 1; off < 256; off <<= 1) {
        int t = (threadIdx.x >= off) ? s[threadIdx.x - off] : 0;
        __syncthreads();
        s[threadIdx.x] += t;
        __syncthreads();
    }
    incl[i] = s[threadIdx.x];
    if (threadIdx.x == 255) bsum[blockIdx.x] = s[255];
}

// ---------------- scan step B: scan the 391 block sums (single block) ----------------
__launch_bounds__(512)
__global__ void scanB(int* __restrict__ bsum) {
    __shared__ int s[512];
    int tid = threadIdx.x;
    int v = (tid < NBLK) ? bsum[tid] : 0;
    s[tid] = v;
    __syncthreads();
#pragma unroll
    for (int off = 1; off < 512; off <<= 1) {
        int t = (tid >= off) ? s[tid - off] : 0;
        __syncthreads();
        s[tid] += t;
        __syncthreads();
    }
    if (tid < NBLK) bsum[tid] = s[tid] - v; // exclusive
}

// ---------------- scan step C: row starts + cursor ----------------
__launch_bounds__(256)
__global__ void scanC(const int* __restrict__ incl, const int* __restrict__ degI,
                      const int* __restrict__ bsum, int* __restrict__ start,
                      int* __restrict__ cursor) {
    int i = blockIdx.x * 256 + threadIdx.x;
    if (i < NN) {
        int st = incl[i] - degI[i] + bsum[blockIdx.x];
        start[i] = st;
        cursor[i] = st;
    }
}

// ---------------- CSR fill ----------------
__global__ void fill_csr(const int* __restrict__ src, const int* __restrict__ dst,
                         int* __restrict__ cursor, int* __restrict__ adj) {
    int e = blockIdx.x * blockDim.x + threadIdx.x;
    if (e < NE) {
        int d = dst[e];
        int pos = atomicAdd(&cursor[d], 1);
        adj[pos] = src[e];
    }
}

// ---------------- layer 1: gather-mean(d=8) + GEMV + ReLU ----------------
// block 256 = 8 nodes x 32 lanes; lane = ch(0..7) + 8*grp(0..3)
__launch_bounds__(256)
__global__ void layer1_fused(const float* __restrict__ x, const int* __restrict__ degI,
                             const int* __restrict__ start, const int* __restrict__ adj,
                             const float* __restrict__ Wl, const float* __restrict__ bl,
                             const float* __restrict__ Wr, float* __restrict__ hout) {
    __shared__ float sWl[DIN * DH];
    __shared__ float sWr[DIN * DH];
    __shared__ float sbl[DH];
    __shared__ float sme[8][DIN + 1];
    __shared__ float sxr[8][DIN + 1];

    int tid = threadIdx.x;
    sWl[tid] = Wl[tid];
    sWr[tid] = Wr[tid];
    if (tid < DH) sbl[tid] = bl[tid];

    int n = tid >> 5;
    int t = tid & 31;
    int ch = t & 7, grp = t >> 3;
    int node = blockIdx.x * 8 + n;

    int dg = degI[node];
    int row = start[node];
    float part = 0.0f;
    for (int i = grp; i < dg; i += 4)
        part += x[adj[row + i] * DIN + ch];
    part += __shfl_xor(part, 8);
    part += __shfl_xor(part, 16);
    if (t < 8) {
        sme[n][ch] = part / fmaxf((float)dg, 1.0f);
        sxr[n][ch] = x[node * DIN + ch];
    }
    __syncthreads();

    int j = t;
    float acc = sbl[j];
#pragma unroll
    for (int k = 0; k < DIN; ++k)
        acc += sme[n][k] * sWl[k * DH + j] + sxr[n][k] * sWr[k * DH + j];
    hout[node * DH + j] = fmaxf(acc, 0.0f);
}

// ---------------- layer 2: gather-mean(d=32) + GEMV + ReLU ----------------
__launch_bounds__(256)
__global__ void layer2_fused(const float* __restrict__ hin, const int* __restrict__ degI,
                             const int* __restrict__ start, const int* __restrict__ adj,
                             const float* __restrict__ Wl, const float* __restrict__ bl,
                             const float* __restrict__ Wr, float* __restrict__ hout) {
    __shared__ float sWl[DH * DH];
    __shared__ float sWr[DH * DH];
    __shared__ float sbl[DH];
    __shared__ float sme[8][DH + 1];
    __shared__ float sxr[8][DH + 1];

    int tid = threadIdx.x;
#pragma unroll
    for (int i = 0; i < 4; ++i) {
        sWl[tid + 256 * i] = Wl[tid + 256 * i];
        sWr[tid + 256 * i] = Wr[tid + 256 * i];
    }
    if (tid < DH) sbl[tid] = bl[tid];

    int n = tid >> 5;
    int j = tid & 31;
    int node = blockIdx.x * 8 + n;

    int dg = degI[node];
    int row = start[node];
    float acc = 0.0f;
    int i = 0;
    for (; i + 1 < dg; i += 2) {
        int s0 = adj[row + i];
        int s1 = adj[row + i + 1];
        acc += hin[s0 * DH + j];
        acc += hin[s1 * DH + j];
    }
    if (i < dg) acc += hin[adj[row + i] * DH + j];

    sme[n][j] = acc / fmaxf((float)dg, 1.0f);
    sxr[n][j] = hin[node * DH + j];
    __syncthreads();

    float acc2 = sbl[j];
#pragma unroll
    for (int k = 0; k < DH; ++k)
        acc2 += sme[n][k] * sWl[k * DH + j] + sxr[n][k] * sWr[k * DH + j];
    hout[node * DH + j] = fmaxf(acc2, 0.0f);
}

// ---------------- layer 3 + MLP head ----------------
__launch_bounds__(256)
__global__ void layer3_head(const float* __restrict__ hin, const int* __restrict__ degI,
                            const int* __restrict__ start, const int* __restrict__ adj,
                            const float* __restrict__ Wl, const float* __restrict__ bl,
                            const float* __restrict__ Wr,
                            const float* __restrict__ Wh1, const float* __restrict__ bh1,
                            const float* __restrict__ Wh2, const float* __restrict__ bh2,
                            float* __restrict__ out) {
    __shared__ float sWl[DH * DH];
    __shared__ float sWr[DH * DH];
    __shared__ float sWh1[DH * DH];
    __shared__ float sWh2[DH * NACT];
    __shared__ float sbl[DH];
    __shared__ float sbh1[DH];
    __shared__ float sbh2[NACT];
    __shared__ float sme[8][DH + 1];
    __shared__ float sxr[8][DH + 1];
    __shared__ float sh3[8][DH + 1];
    __shared__ float shh[8][DH + 1];

    int tid = threadIdx.x;
#pragma unroll
    for (int i = 0; i < 4; ++i) {
        sWl[tid + 256 * i] = Wl[tid + 256 * i];
        sWr[tid + 256 * i] = Wr[tid + 256 * i];
        sWh1[tid + 256 * i] = Wh1[tid + 256 * i];
    }
    if (tid < DH * NACT) sWh2[tid] = Wh2[tid];
    if (tid < DH) { sbl[tid] = bl[tid]; sbh1[tid] = bh1[tid]; }
    if (tid < NACT) sbh2[tid] = bh2[tid];

    int n = tid >> 5;
    int j = tid & 31;
    int node = blockIdx.x * 8 + n;

    int dg = degI[node];
    int row = start[node];
    float acc = 0.0f;
    int i = 0;
    for (; i + 1 < dg; i += 2) {
        int s0 = adj[row + i];
        int s1 = adj[row + i + 1];
        acc += hin[s0 * DH + j];
        acc += hin[s1 * DH + j];
    }
    if (i < dg) acc += hin[adj[row + i] * DH + j];

    sme[n][j] = acc / fmaxf((float)dg, 1.0f);
    sxr[n][j] = hin[node * DH + j];
    __syncthreads();

    float a1 = sbl[j];
#pragma unroll
    for (int k = 0; k < DH; ++k)
        a1 += sme[n][k] * sWl[k * DH + j] + sxr[n][k] * sWr[k * DH + j];
    sh3[n][j] = fmaxf(a1, 0.0f);
    __syncthreads();

    float a2 = sbh1[j];
#pragma unroll
    for (int k = 0; k < DH; ++k)
        a2 += sh3[n][k] * sWh1[k * DH + j];
    shh[n][j] = fmaxf(a2, 0.0f);
    __syncthreads();

    if (j < NACT) {
        float o = sbh2[j];
#pragma unroll
        for (int k = 0; k < DH; ++k)
            o += shh[n][k] * sWh2[k * NACT + j];
        out[node * NACT + j] = o;
    }
}

extern "C" void kernel_launch(void* const* d_in, const int* in_sizes, int n_in,
                              void* d_out, int out_size, void* d_ws, size_t ws_size,
                              hipStream_t stream) {
    const float* x   = (const float*)d_in[0];
    const int*   ei  = (const int*)d_in[1];
    const int*   src = ei;
    const int*   dst = ei + NE;
    const float* Wl1 = (const float*)d_in[2];
    const float* bl1 = (const float*)d_in[3];
    const float* Wr1 = (const float*)d_in[4];
    const float* Wl2 = (const float*)d_in[5];
    const float* bl2 = (const float*)d_in[6];
    const float* Wr2 = (const float*)d_in[7];
    const float* Wl3 = (const float*)d_in[8];
    const float* bl3 = (const float*)d_in[9];
    const float* Wr3 = (const float*)d_in[10];
    const float* Wh1 = (const float*)d_in[11];
    const float* bh1 = (const float*)d_in[12];
    const float* Wh2 = (const float*)d_in[13];
    const float* bh2 = (const float*)d_in[14];
    float* out = (float*)d_out;

    int* degI   = (int*)d_ws;            // NN
    int* startP = degI + NN;             // NN
    int* cursor = startP + NN;           // NN
    int* bsum   = cursor + NN;           // 512
    int* incl   = bsum + 512;            // PADN
    int* adj    = incl + PADN;           // NE
    float* hA   = (float*)(adj + NE);    // 32N
    float* hB   = hA + DH * NN;          // 32N

    hipMemsetAsync(degI, 0, NN * sizeof(int), stream);

    // ---- build CSR ----
    count_deg<<<(NE + 255) / 256, 256, 0, stream>>>(dst, degI);
    scanA<<<NBLK, 256, 0, stream>>>(degI, incl, bsum);
    scanB<<<1, 512, 0, stream>>>(bsum);
    scanC<<<NBLK, 256, 0, stream>>>(incl, degI, bsum, startP, cursor);
    fill_csr<<<(NE + 255) / 256, 256, 0, stream>>>(src, dst, cursor, adj);

    // ---- layers ----
    layer1_fused<<<NN / 8, 256, 0, stream>>>(x, degI, startP, adj, Wl1, bl1, Wr1, hA);
    layer2_fused<<<NN / 8, 256, 0, stream>>>(hA, degI, startP, adj, Wl2, bl2, Wr2, hB);
    layer3_head<<<NN / 8, 256, 0, stream>>>(hB, degI, startP, adj, Wl3, bl3, Wr3,
                                            Wh1, bh1, Wh2, bh2, out);
}

// Round 3
// 399.556 us; speedup vs baseline: 4.7308x; 1.1897x over previous
//
#include <hip/hip_runtime.h>
#include <hip/hip_bf16.h>

#define NN 100000
#define NE 1600000
#define DIN 8
#define DH 32
#define NACT 3
#define NBLK 391          // ceil(NN/256)
#define PADN (NBLK * 256)
#define NRANGE 12500      // NN / 8 (nodes per XCD-range)
#define CHUNKS 192
#define EC ((NE + CHUNKS - 1) / CHUNKS)   // 8334 edges per chunk

typedef __hip_bfloat16 bf;

// ---------------- degree count, XCD-partitioned ----------------
// blockIdx&7 selects the dst-range; consecutive blockIdx round-robin XCDs,
// so all atomics to degI[range g] stay in one XCD's L2.
__launch_bounds__(256)
__global__ void count_deg_part(const int* __restrict__ dst, int* __restrict__ degI) {
    int g = blockIdx.x & 7;
    int chunk = blockIdx.x >> 3;
    int lo = g * NRANGE;
    int e0 = chunk * EC;
    int e1 = min(e0 + EC, NE);
    for (int e = e0 + (int)threadIdx.x; e < e1; e += 256) {
        int d = dst[e];
        if ((unsigned)(d - lo) < (unsigned)NRANGE)
            atomicAdd(&degI[d], 1);
    }
}

// ---------------- scan step A: per-block inclusive scan ----------------
__launch_bounds__(256)
__global__ void scanA(const int* __restrict__ degI, int* __restrict__ incl,
                      int* __restrict__ bsum) {
    __shared__ int s[256];
    int i = blockIdx.x * 256 + threadIdx.x;
    int v = (i < NN) ? degI[i] : 0;
    s[threadIdx.x] = v;
    __syncthreads();
#pragma unroll
    for (int off = 1; off < 256; off <<= 1) {
        int t = (threadIdx.x >= off) ? s[threadIdx.x - off] : 0;
        __syncthreads();
        s[threadIdx.x] += t;
        __syncthreads();
    }
    incl[i] = s[threadIdx.x];
    if (threadIdx.x == 255) bsum[blockIdx.x] = s[255];
}

// ---------------- scan step B: scan 391 block sums ----------------
__launch_bounds__(512)
__global__ void scanB(int* __restrict__ bsum) {
    __shared__ int s[512];
    int tid = threadIdx.x;
    int v = (tid < NBLK) ? bsum[tid] : 0;
    s[tid] = v;
    __syncthreads();
#pragma unroll
    for (int off = 1; off < 512; off <<= 1) {
        int t = (tid >= off) ? s[tid - off] : 0;
        __syncthreads();
        s[tid] += t;
        __syncthreads();
    }
    if (tid < NBLK) bsum[tid] = s[tid] - v; // exclusive
}

// ---------------- scan step C: row starts + cursor ----------------
__launch_bounds__(256)
__global__ void scanC(const int* __restrict__ incl, const int* __restrict__ degI,
                      const int* __restrict__ bsum, int* __restrict__ start,
                      int* __restrict__ cursor) {
    int i = blockIdx.x * 256 + threadIdx.x;
    if (i < NN) {
        int st = incl[i] - degI[i] + bsum[blockIdx.x];
        start[i] = st;
        cursor[i] = st;
    }
}

// ---------------- CSR fill, XCD-partitioned ----------------
__launch_bounds__(256)
__global__ void fill_csr_part(const int* __restrict__ src, const int* __restrict__ dst,
                              int* __restrict__ cursor, int* __restrict__ adj) {
    int g = blockIdx.x & 7;
    int chunk = blockIdx.x >> 3;
    int lo = g * NRANGE;
    int e0 = chunk * EC;
    int e1 = min(e0 + EC, NE);
    for (int e = e0 + (int)threadIdx.x; e < e1; e += 256) {
        int d = dst[e];
        if ((unsigned)(d - lo) < (unsigned)NRANGE) {
            int pos = atomicAdd(&cursor[d], 1);
            adj[pos] = src[e];
        }
    }
}

// ---------------- layer 1: gather-mean(d=8) + GEMV + ReLU -> bf16 ----------------
// block 256 = 8 nodes x 32 lanes; lane = ch(0..7) + 8*grp(0..3)
__launch_bounds__(256)
__global__ void layer1_fused(const float* __restrict__ x, const int* __restrict__ degI,
                             const int* __restrict__ start, const int* __restrict__ adj,
                             const float* __restrict__ Wl, const float* __restrict__ bl,
                             const float* __restrict__ Wr, bf* __restrict__ hout) {
    __shared__ float sWl[DIN * DH];
    __shared__ float sWr[DIN * DH];
    __shared__ float sbl[DH];
    __shared__ float sme[8][DIN + 1];
    __shared__ float sxr[8][DIN + 1];

    int tid = threadIdx.x;
    sWl[tid] = Wl[tid];
    sWr[tid] = Wr[tid];
    if (tid < DH) sbl[tid] = bl[tid];

    int n = tid >> 5;
    int t = tid & 31;
    int ch = t & 7, grp = t >> 3;
    int node = blockIdx.x * 8 + n;

    int dg = degI[node];
    int row = start[node];
    float part = 0.0f;
    for (int i = grp; i < dg; i += 4)
        part += x[adj[row + i] * DIN + ch];
    part += __shfl_xor(part, 8);
    part += __shfl_xor(part, 16);
    if (t < 8) {
        sme[n][ch] = part / fmaxf((float)dg, 1.0f);
        sxr[n][ch] = x[node * DIN + ch];
    }
    __syncthreads();

    int j = t;
    float acc = sbl[j];
#pragma unroll
    for (int k = 0; k < DIN; ++k)
        acc += sme[n][k] * sWl[k * DH + j] + sxr[n][k] * sWr[k * DH + j];
    hout[node * DH + j] = __float2bfloat16(fmaxf(acc, 0.0f));
}

// ---------------- layer 2: bf16 gather-mean(d=32) + GEMV + ReLU -> bf16 --------
__launch_bounds__(256)
__global__ void layer2_fused(const bf* __restrict__ hin, const int* __restrict__ degI,
                             const int* __restrict__ start, const int* __restrict__ adj,
                             const float* __restrict__ Wl, const float* __restrict__ bl,
                             const float* __restrict__ Wr, bf* __restrict__ hout) {
    __shared__ float sWl[DH * DH];
    __shared__ float sWr[DH * DH];
    __shared__ float sbl[DH];
    __shared__ float sme[8][DH + 1];
    __shared__ float sxr[8][DH + 1];

    int tid = threadIdx.x;
#pragma unroll
    for (int i = 0; i < 4; ++i) {
        sWl[tid + 256 * i] = Wl[tid + 256 * i];
        sWr[tid + 256 * i] = Wr[tid + 256 * i];
    }
    if (tid < DH) sbl[tid] = bl[tid];

    int n = tid >> 5;
    int j = tid & 31;
    int node = blockIdx.x * 8 + n;

    int dg = degI[node];
    int row = start[node];
    float acc = 0.0f;
    int i = 0;
    for (; i + 3 < dg; i += 4) {
        int s0 = adj[row + i];
        int s1 = adj[row + i + 1];
        int s2 = adj[row + i + 2];
        int s3 = adj[row + i + 3];
        acc += __bfloat162float(hin[s0 * DH + j]);
        acc += __bfloat162float(hin[s1 * DH + j]);
        acc += __bfloat162float(hin[s2 * DH + j]);
        acc += __bfloat162float(hin[s3 * DH + j]);
    }
    for (; i < dg; ++i)
        acc += __bfloat162float(hin[adj[row + i] * DH + j]);

    sme[n][j] = acc / fmaxf((float)dg, 1.0f);
    sxr[n][j] = __bfloat162float(hin[node * DH + j]);
    __syncthreads();

    float acc2 = sbl[j];
#pragma unroll
    for (int k = 0; k < DH; ++k)
        acc2 += sme[n][k] * sWl[k * DH + j] + sxr[n][k] * sWr[k * DH + j];
    hout[node * DH + j] = __float2bfloat16(fmaxf(acc2, 0.0f));
}

// ---------------- layer 3 + MLP head (bf16 in, f32 out) ----------------
__launch_bounds__(256)
__global__ void layer3_head(const bf* __restrict__ hin, const int* __restrict__ degI,
                            const int* __restrict__ start, const int* __restrict__ adj,
                            const float* __restrict__ Wl, const float* __restrict__ bl,
                            const float* __restrict__ Wr,
                            const float* __restrict__ Wh1, const float* __restrict__ bh1,
                            const float* __restrict__ Wh2, const float* __restrict__ bh2,
                            float* __restrict__ out) {
    __shared__ float sWl[DH * DH];
    __shared__ float sWr[DH * DH];
    __shared__ float sWh1[DH * DH];
    __shared__ float sWh2[DH * NACT];
    __shared__ float sbl[DH];
    __shared__ float sbh1[DH];
    __shared__ float sbh2[NACT];
    __shared__ float sme[8][DH + 1];
    __shared__ float sxr[8][DH + 1];
    __shared__ float sh3[8][DH + 1];
    __shared__ float shh[8][DH + 1];

    int tid = threadIdx.x;
#pragma unroll
    for (int i = 0; i < 4; ++i) {
        sWl[tid + 256 * i] = Wl[tid + 256 * i];
        sWr[tid + 256 * i] = Wr[tid + 256 * i];
        sWh1[tid + 256 * i] = Wh1[tid + 256 * i];
    }
    if (tid < DH * NACT) sWh2[tid] = Wh2[tid];
    if (tid < DH) { sbl[tid] = bl[tid]; sbh1[tid] = bh1[tid]; }
    if (tid < NACT) sbh2[tid] = bh2[tid];

    int n = tid >> 5;
    int j = tid & 31;
    int node = blockIdx.x * 8 + n;

    int dg = degI[node];
    int row = start[node];
    float acc = 0.0f;
    int i = 0;
    for (; i + 3 < dg; i += 4) {
        int s0 = adj[row + i];
        int s1 = adj[row + i + 1];
        int s2 = adj[row + i + 2];
        int s3 = adj[row + i + 3];
        acc += __bfloat162float(hin[s0 * DH + j]);
        acc += __bfloat162float(hin[s1 * DH + j]);
        acc += __bfloat162float(hin[s2 * DH + j]);
        acc += __bfloat162float(hin[s3 * DH + j]);
    }
    for (; i < dg; ++i)
        acc += __bfloat162float(hin[adj[row + i] * DH + j]);

    sme[n][j] = acc / fmaxf((float)dg, 1.0f);
    sxr[n][j] = __bfloat162float(hin[node * DH + j]);
    __syncthreads();

    float a1 = sbl[j];
#pragma unroll
    for (int k = 0; k < DH; ++k)
        a1 += sme[n][k] * sWl[k * DH + j] + sxr[n][k] * sWr[k * DH + j];
    sh3[n][j] = fmaxf(a1, 0.0f);
    __syncthreads();

    float a2 = sbh1[j];
#pragma unroll
    for (int k = 0; k < DH; ++k)
        a2 += sh3[n][k] * sWh1[k * DH + j];
    shh[n][j] = fmaxf(a2, 0.0f);
    __syncthreads();

    if (j < NACT) {
        float o = sbh2[j];
#pragma unroll
        for (int k = 0; k < DH; ++k)
            o += shh[n][k] * sWh2[k * NACT + j];
        out[node * NACT + j] = o;
    }
}

extern "C" void kernel_launch(void* const* d_in, const int* in_sizes, int n_in,
                              void* d_out, int out_size, void* d_ws, size_t ws_size,
                              hipStream_t stream) {
    const float* x   = (const float*)d_in[0];
    const int*   ei  = (const int*)d_in[1];
    const int*   src = ei;
    const int*   dst = ei + NE;
    const float* Wl1 = (const float*)d_in[2];
    const float* bl1 = (const float*)d_in[3];
    const float* Wr1 = (const float*)d_in[4];
    const float* Wl2 = (const float*)d_in[5];
    const float* bl2 = (const float*)d_in[6];
    const float* Wr2 = (const float*)d_in[7];
    const float* Wl3 = (const float*)d_in[8];
    const float* bl3 = (const float*)d_in[9];
    const float* Wr3 = (const float*)d_in[10];
    const float* Wh1 = (const float*)d_in[11];
    const float* bh1 = (const float*)d_in[12];
    const float* Wh2 = (const float*)d_in[13];
    const float* bh2 = (const float*)d_in[14];
    float* out = (float*)d_out;

    int* degI   = (int*)d_ws;            // NN
    int* startP = degI + NN;             // NN
    int* cursor = startP + NN;           // NN
    int* bsum   = cursor + NN;           // 512
    int* incl   = bsum + 512;            // PADN
    int* adj    = incl + PADN;           // NE
    bf*  hA     = (bf*)(adj + NE);       // DH*NN bf16
    bf*  hB     = hA + DH * NN;          // DH*NN bf16

    hipMemsetAsync(degI, 0, NN * sizeof(int), stream);

    // ---- build CSR (XCD-partitioned histogram + fill) ----
    count_deg_part<<<CHUNKS * 8, 256, 0, stream>>>(dst, degI);
    scanA<<<NBLK, 256, 0, stream>>>(degI, incl, bsum);
    scanB<<<1, 512, 0, stream>>>(bsum);
    scanC<<<NBLK, 256, 0, stream>>>(incl, degI, bsum, startP, cursor);
    fill_csr_part<<<CHUNKS * 8, 256, 0, stream>>>(src, dst, cursor, adj);

    // ---- layers ----
    layer1_fused<<<NN / 8, 256, 0, stream>>>(x, degI, startP, adj, Wl1, bl1, Wr1, hA);
    layer2_fused<<<NN / 8, 256, 0, stream>>>(hA, degI, startP, adj, Wl2, bl2, Wr2, hB);
    layer3_head<<<NN / 8, 256, 0, stream>>>(hB, degI, startP, adj, Wl3, bl3, Wr3,
                                            Wh1, bh1, Wh2, bh2, out);
}

// Round 4
// 375.892 us; speedup vs baseline: 5.0286x; 1.0630x over previous
//
#include <hip/hip_runtime.h>
#include <hip/hip_bf16.h>

#define NN 100000
#define NE 1600000
#define DIN 8
#define DH 32
#define NACT 3
#define NBLK 391          // ceil(NN/256)
#define PADN (NBLK * 256)
#define NRANGE 12500      // NN / 8 (nodes per XCD-range)
#define CHUNKS 125
#define EC (NE / CHUNKS)  // 12800 edges per chunk, multiple of 4

typedef __hip_bfloat16 bf;

__device__ __forceinline__ float bflo(unsigned u) { return __uint_as_float(u << 16); }
__device__ __forceinline__ float bfhi(unsigned u) { return __uint_as_float(u & 0xffff0000u); }

// ---------------- degree count, XCD-partitioned, int4 reads ----------------
__launch_bounds__(256)
__global__ void count_deg_part(const int* __restrict__ dst, int* __restrict__ degI) {
    int g = blockIdx.x & 7;
    int chunk = blockIdx.x >> 3;
    int lo = g * NRANGE;
    int e0 = chunk * EC;
    for (int e = e0 + (int)threadIdx.x * 4; e < e0 + EC; e += 1024) {
        int4 d4 = *reinterpret_cast<const int4*>(&dst[e]);
        if ((unsigned)(d4.x - lo) < (unsigned)NRANGE) atomicAdd(&degI[d4.x], 1);
        if ((unsigned)(d4.y - lo) < (unsigned)NRANGE) atomicAdd(&degI[d4.y], 1);
        if ((unsigned)(d4.z - lo) < (unsigned)NRANGE) atomicAdd(&degI[d4.z], 1);
        if ((unsigned)(d4.w - lo) < (unsigned)NRANGE) atomicAdd(&degI[d4.w], 1);
    }
}

// ---------------- scan step A ----------------
__launch_bounds__(256)
__global__ void scanA(const int* __restrict__ degI, int* __restrict__ incl,
                      int* __restrict__ bsum) {
    __shared__ int s[256];
    int i = blockIdx.x * 256 + threadIdx.x;
    int v = (i < NN) ? degI[i] : 0;
    s[threadIdx.x] = v;
    __syncthreads();
#pragma unroll
    for (int off = 1; off < 256; off <<= 1) {
        int t = (threadIdx.x >= off) ? s[threadIdx.x - off] : 0;
        __syncthreads();
        s[threadIdx.x] += t;
        __syncthreads();
    }
    incl[i] = s[threadIdx.x];
    if (threadIdx.x == 255) bsum[blockIdx.x] = s[255];
}

// ---------------- scan step B ----------------
__launch_bounds__(512)
__global__ void scanB(int* __restrict__ bsum) {
    __shared__ int s[512];
    int tid = threadIdx.x;
    int v = (tid < NBLK) ? bsum[tid] : 0;
    s[tid] = v;
    __syncthreads();
#pragma unroll
    for (int off = 1; off < 512; off <<= 1) {
        int t = (tid >= off) ? s[tid - off] : 0;
        __syncthreads();
        s[tid] += t;
        __syncthreads();
    }
    if (tid < NBLK) bsum[tid] = s[tid] - v; // exclusive
}

// ---------------- scan step C ----------------
__launch_bounds__(256)
__global__ void scanC(const int* __restrict__ incl, const int* __restrict__ degI,
                      const int* __restrict__ bsum, int* __restrict__ start,
                      int* __restrict__ cursor) {
    int i = blockIdx.x * 256 + threadIdx.x;
    if (i < NN) {
        int st = incl[i] - degI[i] + bsum[blockIdx.x];
        start[i] = st;
        cursor[i] = st;
    }
}

// ---------------- CSR fill, XCD-partitioned, int4 reads ----------------
__launch_bounds__(256)
__global__ void fill_csr_part(const int* __restrict__ src, const int* __restrict__ dst,
                              int* __restrict__ cursor, int* __restrict__ adj) {
    int g = blockIdx.x & 7;
    int chunk = blockIdx.x >> 3;
    int lo = g * NRANGE;
    int e0 = chunk * EC;
    for (int e = e0 + (int)threadIdx.x * 4; e < e0 + EC; e += 1024) {
        int4 d4 = *reinterpret_cast<const int4*>(&dst[e]);
        int4 s4 = *reinterpret_cast<const int4*>(&src[e]);
        if ((unsigned)(d4.x - lo) < (unsigned)NRANGE) adj[atomicAdd(&cursor[d4.x], 1)] = s4.x;
        if ((unsigned)(d4.y - lo) < (unsigned)NRANGE) adj[atomicAdd(&cursor[d4.y], 1)] = s4.y;
        if ((unsigned)(d4.z - lo) < (unsigned)NRANGE) adj[atomicAdd(&cursor[d4.z], 1)] = s4.z;
        if ((unsigned)(d4.w - lo) < (unsigned)NRANGE) adj[atomicAdd(&cursor[d4.w], 1)] = s4.w;
    }
}

// ---------------- layer 1: gather-mean(d=8, f32, float2 lanes) + GEMV -> bf16 ----
// lane = nb(0..7)*4 + c2(0..3); each lane loads float2 (channels 2c2, 2c2+1)
__launch_bounds__(256)
__global__ void layer1_fused(const float* __restrict__ x, const int* __restrict__ degI,
                             const int* __restrict__ start, const int* __restrict__ adj,
                             const float* __restrict__ Wl, const float* __restrict__ bl,
                             const float* __restrict__ Wr, bf* __restrict__ hout) {
    __shared__ float sWl[DIN * DH];
    __shared__ float sWr[DIN * DH];
    __shared__ float sbl[DH];
    __shared__ float sme[8][DIN];
    __shared__ float sxr[8][DIN];

    int tid = threadIdx.x;
    sWl[tid] = Wl[tid];
    sWr[tid] = Wr[tid];
    if (tid < DH) sbl[tid] = bl[tid];

    int n = tid >> 5;
    int t = tid & 31;
    int nb = t >> 2;   // 0..7
    int c2 = t & 3;    // channel pair
    int node = blockIdx.x * 8 + n;

    int dg = degI[node];
    int row = start[node];
    float a0 = 0.0f, a1 = 0.0f;
    for (int i = 0; i < dg; i += 8) {
        int idx = i + nb;
        bool v = idx < dg;
        int s = v ? adj[row + idx] : node;
        float2 vv = *reinterpret_cast<const float2*>(&x[s * DIN + c2 * 2]);
        if (v) { a0 += vv.x; a1 += vv.y; }
    }
    a0 += __shfl_xor(a0, 4);  a1 += __shfl_xor(a1, 4);
    a0 += __shfl_xor(a0, 8);  a1 += __shfl_xor(a1, 8);
    a0 += __shfl_xor(a0, 16); a1 += __shfl_xor(a1, 16);
    if (t < 4) {
        float inv = 1.0f / fmaxf((float)dg, 1.0f);
        sme[n][c2 * 2 + 0] = a0 * inv;
        sme[n][c2 * 2 + 1] = a1 * inv;
    }
    if (t < 8) sxr[n][t] = x[node * DIN + t];
    __syncthreads();

    int j = t;
    float acc = sbl[j];
#pragma unroll
    for (int k = 0; k < DIN; ++k)
        acc += sme[n][k] * sWl[k * DH + j] + sxr[n][k] * sWr[k * DH + j];
    hout[node * DH + j] = __float2bfloat16(fmaxf(acc, 0.0f));
}

// ---------------- layer 2: gather-mean(d=32, bf16, uint2 lanes) + GEMV -> bf16 --
// lane = nb(0..3)*8 + c4(0..7); each lane loads uint2 = 4 bf16 (channels 4c4..4c4+3)
__launch_bounds__(256)
__global__ void layer2_fused(const bf* __restrict__ hin, const int* __restrict__ degI,
                             const int* __restrict__ start, const int* __restrict__ adj,
                             const float* __restrict__ Wl, const float* __restrict__ bl,
                             const float* __restrict__ Wr, bf* __restrict__ hout) {
    __shared__ float sWl[DH * DH];
    __shared__ float sWr[DH * DH];
    __shared__ float sbl[DH];
    __shared__ float sme[8][DH];
    __shared__ float sxr[8][DH];

    int tid = threadIdx.x;
#pragma unroll
    for (int i = 0; i < 4; ++i) {
        sWl[tid + 256 * i] = Wl[tid + 256 * i];
        sWr[tid + 256 * i] = Wr[tid + 256 * i];
    }
    if (tid < DH) sbl[tid] = bl[tid];

    int n = tid >> 5;
    int t = tid & 31;
    int nb = t >> 3;   // 0..3
    int c4 = t & 7;    // channel quad
    int node = blockIdx.x * 8 + n;

    int dg = degI[node];
    int row = start[node];
    float a0 = 0.0f, a1 = 0.0f, a2 = 0.0f, a3 = 0.0f;
    for (int i = 0; i < dg; i += 4) {
        int idx = i + nb;
        bool v = idx < dg;
        int s = v ? adj[row + idx] : node;
        uint2 u = *reinterpret_cast<const uint2*>(&hin[s * DH + c4 * 4]);
        if (v) {
            a0 += bflo(u.x); a1 += bfhi(u.x);
            a2 += bflo(u.y); a3 += bfhi(u.y);
        }
    }
    a0 += __shfl_xor(a0, 8);  a1 += __shfl_xor(a1, 8);
    a2 += __shfl_xor(a2, 8);  a3 += __shfl_xor(a3, 8);
    a0 += __shfl_xor(a0, 16); a1 += __shfl_xor(a1, 16);
    a2 += __shfl_xor(a2, 16); a3 += __shfl_xor(a3, 16);
    if (t < 8) {
        float inv = 1.0f / fmaxf((float)dg, 1.0f);
        sme[n][c4 * 4 + 0] = a0 * inv;
        sme[n][c4 * 4 + 1] = a1 * inv;
        sme[n][c4 * 4 + 2] = a2 * inv;
        sme[n][c4 * 4 + 3] = a3 * inv;
    }
    sxr[n][t] = __bfloat162float(hin[node * DH + t]);
    __syncthreads();

    int j = t;
    float acc2 = sbl[j];
#pragma unroll
    for (int k = 0; k < DH; ++k)
        acc2 += sme[n][k] * sWl[k * DH + j] + sxr[n][k] * sWr[k * DH + j];
    hout[node * DH + j] = __float2bfloat16(fmaxf(acc2, 0.0f));
}

// ---------------- layer 3 + MLP head (bf16 in, f32 out) ----------------
__launch_bounds__(256)
__global__ void layer3_head(const bf* __restrict__ hin, const int* __restrict__ degI,
                            const int* __restrict__ start, const int* __restrict__ adj,
                            const float* __restrict__ Wl, const float* __restrict__ bl,
                            const float* __restrict__ Wr,
                            const float* __restrict__ Wh1, const float* __restrict__ bh1,
                            const float* __restrict__ Wh2, const float* __restrict__ bh2,
                            float* __restrict__ out) {
    __shared__ float sWl[DH * DH];
    __shared__ float sWr[DH * DH];
    __shared__ float sWh1[DH * DH];
    __shared__ float sWh2[DH * NACT];
    __shared__ float sbl[DH];
    __shared__ float sbh1[DH];
    __shared__ float sbh2[NACT];
    __shared__ float sme[8][DH];
    __shared__ float sxr[8][DH];
    __shared__ float sh3[8][DH];
    __shared__ float shh[8][DH];

    int tid = threadIdx.x;
#pragma unroll
    for (int i = 0; i < 4; ++i) {
        sWl[tid + 256 * i] = Wl[tid + 256 * i];
        sWr[tid + 256 * i] = Wr[tid + 256 * i];
        sWh1[tid + 256 * i] = Wh1[tid + 256 * i];
    }
    if (tid < DH * NACT) sWh2[tid] = Wh2[tid];
    if (tid < DH) { sbl[tid] = bl[tid]; sbh1[tid] = bh1[tid]; }
    if (tid < NACT) sbh2[tid] = bh2[tid];

    int n = tid >> 5;
    int t = tid & 31;
    int nb = t >> 3;
    int c4 = t & 7;
    int node = blockIdx.x * 8 + n;

    int dg = degI[node];
    int row = start[node];
    float a0 = 0.0f, a1 = 0.0f, a2 = 0.0f, a3 = 0.0f;
    for (int i = 0; i < dg; i += 4) {
        int idx = i + nb;
        bool v = idx < dg;
        int s = v ? adj[row + idx] : node;
        uint2 u = *reinterpret_cast<const uint2*>(&hin[s * DH + c4 * 4]);
        if (v) {
            a0 += bflo(u.x); a1 += bfhi(u.x);
            a2 += bflo(u.y); a3 += bfhi(u.y);
        }
    }
    a0 += __shfl_xor(a0, 8);  a1 += __shfl_xor(a1, 8);
    a2 += __shfl_xor(a2, 8);  a3 += __shfl_xor(a3, 8);
    a0 += __shfl_xor(a0, 16); a1 += __shfl_xor(a1, 16);
    a2 += __shfl_xor(a2, 16); a3 += __shfl_xor(a3, 16);
    if (t < 8) {
        float inv = 1.0f / fmaxf((float)dg, 1.0f);
        sme[n][c4 * 4 + 0] = a0 * inv;
        sme[n][c4 * 4 + 1] = a1 * inv;
        sme[n][c4 * 4 + 2] = a2 * inv;
        sme[n][c4 * 4 + 3] = a3 * inv;
    }
    sxr[n][t] = __bfloat162float(hin[node * DH + t]);
    __syncthreads();

    int j = t;
    float a1v = sbl[j];
#pragma unroll
    for (int k = 0; k < DH; ++k)
        a1v += sme[n][k] * sWl[k * DH + j] + sxr[n][k] * sWr[k * DH + j];
    sh3[n][j] = fmaxf(a1v, 0.0f);
    __syncthreads();

    float a2v = sbh1[j];
#pragma unroll
    for (int k = 0; k < DH; ++k)
        a2v += sh3[n][k] * sWh1[k * DH + j];
    shh[n][j] = fmaxf(a2v, 0.0f);
    __syncthreads();

    if (j < NACT) {
        float o = sbh2[j];
#pragma unroll
        for (int k = 0; k < DH; ++k)
            o += shh[n][k] * sWh2[k * NACT + j];
        out[node * NACT + j] = o;
    }
}

extern "C" void kernel_launch(void* const* d_in, const int* in_sizes, int n_in,
                              void* d_out, int out_size, void* d_ws, size_t ws_size,
                              hipStream_t stream) {
    const float* x   = (const float*)d_in[0];
    const int*   ei  = (const int*)d_in[1];
    const int*   src = ei;
    const int*   dst = ei + NE;
    const float* Wl1 = (const float*)d_in[2];
    const float* bl1 = (const float*)d_in[3];
    const float* Wr1 = (const float*)d_in[4];
    const float* Wl2 = (const float*)d_in[5];
    const float* bl2 = (const float*)d_in[6];
    const float* Wr2 = (const float*)d_in[7];
    const float* Wl3 = (const float*)d_in[8];
    const float* bl3 = (const float*)d_in[9];
    const float* Wr3 = (const float*)d_in[10];
    const float* Wh1 = (const float*)d_in[11];
    const float* bh1 = (const float*)d_in[12];
    const float* Wh2 = (const float*)d_in[13];
    const float* bh2 = (const float*)d_in[14];
    float* out = (float*)d_out;

    int* degI   = (int*)d_ws;            // NN
    int* startP = degI + NN;             // NN
    int* cursor = startP + NN;           // NN
    int* bsum   = cursor + NN;           // 512
    int* incl   = bsum + 512;            // PADN
    int* adj    = incl + PADN;           // NE
    bf*  hA     = (bf*)(adj + NE);       // DH*NN bf16
    bf*  hB     = hA + DH * NN;          // DH*NN bf16

    hipMemsetAsync(degI, 0, NN * sizeof(int), stream);

    // ---- build CSR (XCD-partitioned histogram + fill) ----
    count_deg_part<<<CHUNKS * 8, 256, 0, stream>>>(dst, degI);
    scanA<<<NBLK, 256, 0, stream>>>(degI, incl, bsum);
    scanB<<<1, 512, 0, stream>>>(bsum);
    scanC<<<NBLK, 256, 0, stream>>>(incl, degI, bsum, startP, cursor);
    fill_csr_part<<<CHUNKS * 8, 256, 0, stream>>>(src, dst, cursor, adj);

    // ---- layers ----
    layer1_fused<<<NN / 8, 256, 0, stream>>>(x, degI, startP, adj, Wl1, bl1, Wr1, hA);
    layer2_fused<<<NN / 8, 256, 0, stream>>>(hA, degI, startP, adj, Wl2, bl2, Wr2, hB);
    layer3_head<<<NN / 8, 256, 0, stream>>>(hB, degI, startP, adj, Wl3, bl3, Wr3,
                                            Wh1, bh1, Wh2, bh2, out);
}

// Round 5
// 375.087 us; speedup vs baseline: 5.0394x; 1.0021x over previous
//
#include <hip/hip_runtime.h>
#include <hip/hip_bf16.h>

#define NN 100000
#define NE 1600000
#define DIN 8
#define DH 32
#define NACT 3
#define NBLK 391          // ceil(NN/256)
#define PADN (NBLK * 256)
#define NRANGE 12500      // NN / 8
#define CHUNKS 125
#define EC (NE / CHUNKS)  // 12800, multiple of 4
#define LGRID ((NN + 63) / 64)   // 1563 blocks x 64 nodes

typedef __hip_bfloat16 bf;
typedef unsigned short u16;
typedef __attribute__((ext_vector_type(8))) short bf16x8;
typedef __attribute__((ext_vector_type(4))) float f32x4;

__device__ __forceinline__ float bflo(unsigned u) { return __uint_as_float(u << 16); }
__device__ __forceinline__ float bfhi(unsigned u) { return __uint_as_float(u & 0xffff0000u); }

// ---------------- weight prep: pack transposed bf16 B-panels ----------------
// B1t[32][32]: k<8 Wl1, k<16 Wr1, else 0.  B2t/B3t[32][64]: Wl|Wr stacked.
// Bh1t[32][32]: Wh1 transposed.
__launch_bounds__(256)
__global__ void prep_weights(const float* __restrict__ Wl1, const float* __restrict__ Wr1,
                             const float* __restrict__ Wl2, const float* __restrict__ Wr2,
                             const float* __restrict__ Wl3, const float* __restrict__ Wr3,
                             const float* __restrict__ Wh1,
                             u16* __restrict__ B1t, u16* __restrict__ B2t,
                             u16* __restrict__ B3t, u16* __restrict__ Bh1t) {
    int tid = threadIdx.x;
    for (int idx = tid; idx < 1024; idx += 256) {
        int j = idx >> 5, k = idx & 31;
        float v = (k < 8) ? Wl1[k * DH + j] : ((k < 16) ? Wr1[(k - 8) * DH + j] : 0.0f);
        reinterpret_cast<bf*>(B1t)[j * 32 + k] = __float2bfloat16(v);
    }
    for (int idx = tid; idx < 2048; idx += 256) {
        int j = idx >> 6, k = idx & 63;
        float v = (k < 32) ? Wl2[k * DH + j] : Wr2[(k - 32) * DH + j];
        reinterpret_cast<bf*>(B2t)[j * 64 + k] = __float2bfloat16(v);
    }
    for (int idx = tid; idx < 2048; idx += 256) {
        int j = idx >> 6, k = idx & 63;
        float v = (k < 32) ? Wl3[k * DH + j] : Wr3[(k - 32) * DH + j];
        reinterpret_cast<bf*>(B3t)[j * 64 + k] = __float2bfloat16(v);
    }
    for (int idx = tid; idx < 1024; idx += 256) {
        int j = idx >> 5, k = idx & 31;
        reinterpret_cast<bf*>(Bh1t)[j * 32 + k] = __float2bfloat16(Wh1[k * DH + j]);
    }
}

// ---------------- degree count, XCD-partitioned, int4 reads ----------------
__launch_bounds__(256)
__global__ void count_deg_part(const int* __restrict__ dst, int* __restrict__ degI) {
    int g = blockIdx.x & 7;
    int chunk = blockIdx.x >> 3;
    int lo = g * NRANGE;
    int e0 = chunk * EC;
    for (int e = e0 + (int)threadIdx.x * 4; e < e0 + EC; e += 1024) {
        int4 d4 = *reinterpret_cast<const int4*>(&dst[e]);
        if ((unsigned)(d4.x - lo) < (unsigned)NRANGE) atomicAdd(&degI[d4.x], 1);
        if ((unsigned)(d4.y - lo) < (unsigned)NRANGE) atomicAdd(&degI[d4.y], 1);
        if ((unsigned)(d4.z - lo) < (unsigned)NRANGE) atomicAdd(&degI[d4.z], 1);
        if ((unsigned)(d4.w - lo) < (unsigned)NRANGE) atomicAdd(&degI[d4.w], 1);
    }
}

// ---------------- scan A/B/C ----------------
__launch_bounds__(256)
__global__ void scanA(const int* __restrict__ degI, int* __restrict__ incl,
                      int* __restrict__ bsum) {
    __shared__ int s[256];
    int i = blockIdx.x * 256 + threadIdx.x;
    int v = (i < NN) ? degI[i] : 0;
    s[threadIdx.x] = v;
    __syncthreads();
#pragma unroll
    for (int off = 1; off < 256; off <<= 1) {
        int t = (threadIdx.x >= off) ? s[threadIdx.x - off] : 0;
        __syncthreads();
        s[threadIdx.x] += t;
        __syncthreads();
    }
    incl[i] = s[threadIdx.x];
    if (threadIdx.x == 255) bsum[blockIdx.x] = s[255];
}

__launch_bounds__(512)
__global__ void scanB(int* __restrict__ bsum) {
    __shared__ int s[512];
    int tid = threadIdx.x;
    int v = (tid < NBLK) ? bsum[tid] : 0;
    s[tid] = v;
    __syncthreads();
#pragma unroll
    for (int off = 1; off < 512; off <<= 1) {
        int t = (tid >= off) ? s[tid - off] : 0;
        __syncthreads();
        s[tid] += t;
        __syncthreads();
    }
    if (tid < NBLK) bsum[tid] = s[tid] - v;
}

__launch_bounds__(256)
__global__ void scanC(const int* __restrict__ incl, const int* __restrict__ degI,
                      const int* __restrict__ bsum, int* __restrict__ start,
                      int* __restrict__ cursor) {
    int i = blockIdx.x * 256 + threadIdx.x;
    if (i < NN) {
        int st = incl[i] - degI[i] + bsum[blockIdx.x];
        start[i] = st;
        cursor[i] = st;
    }
}

// ---------------- CSR fill, XCD-partitioned, int4 reads ----------------
__launch_bounds__(256)
__global__ void fill_csr_part(const int* __restrict__ src, const int* __restrict__ dst,
                              int* __restrict__ cursor, int* __restrict__ adj) {
    int g = blockIdx.x & 7;
    int chunk = blockIdx.x >> 3;
    int lo = g * NRANGE;
    int e0 = chunk * EC;
    for (int e = e0 + (int)threadIdx.x * 4; e < e0 + EC; e += 1024) {
        int4 d4 = *reinterpret_cast<const int4*>(&dst[e]);
        int4 s4 = *reinterpret_cast<const int4*>(&src[e]);
        if ((unsigned)(d4.x - lo) < (unsigned)NRANGE) adj[atomicAdd(&cursor[d4.x], 1)] = s4.x;
        if ((unsigned)(d4.y - lo) < (unsigned)NRANGE) adj[atomicAdd(&cursor[d4.y], 1)] = s4.y;
        if ((unsigned)(d4.z - lo) < (unsigned)NRANGE) adj[atomicAdd(&cursor[d4.z], 1)] = s4.z;
        if ((unsigned)(d4.w - lo) < (unsigned)NRANGE) adj[atomicAdd(&cursor[d4.w], 1)] = s4.w;
    }
}

// ---------------- layer 1: gather-mean(d=8,f32) -> A[64][72] -> MFMA ----------------
__launch_bounds__(256)
__global__ void layer1_mfma(const float* __restrict__ x, const int* __restrict__ degI,
                            const int* __restrict__ start, const int* __restrict__ adj,
                            const u16* __restrict__ Bt, const float* __restrict__ blv,
                            bf* __restrict__ hout) {
    __shared__ short sA[64 * 72];   // [node][k]: k0..7 mean, 8..15 xr, 16..31 zero
    int tid = threadIdx.x;
    int base = blockIdx.x * 64;

    {   // zero pad region k = 16..31 (16 shorts per row)
        int row = tid >> 2, part = tid & 3;
        *reinterpret_cast<uint2*>(&sA[row * 72 + 16 + part * 4]) = make_uint2(0u, 0u);
    }

    int g = tid >> 5, t = tid & 31;
    int nb = t >> 2, c2 = t & 3;
    int nbase = base + g * 8;
    for (int i = 0; i < 8; ++i) {
        int node = nbase + i;
        if (node >= NN) break;
        int dg = degI[node];
        int row = start[node];
        float a0 = 0.0f, a1 = 0.0f;
        for (int idx = nb; idx < dg; idx += 8) {
            int s = adj[row + idx];
            float2 v = *reinterpret_cast<const float2*>(&x[s * DIN + c2 * 2]);
            a0 += v.x; a1 += v.y;
        }
        a0 += __shfl_xor(a0, 4);  a1 += __shfl_xor(a1, 4);
        a0 += __shfl_xor(a0, 8);  a1 += __shfl_xor(a1, 8);
        a0 += __shfl_xor(a0, 16); a1 += __shfl_xor(a1, 16);
        int nrow = g * 8 + i;
        if (t < 4) {
            float inv = 1.0f / fmaxf((float)dg, 1.0f);
            bf* mp = reinterpret_cast<bf*>(&sA[nrow * 72 + t * 2]);
            mp[0] = __float2bfloat16(a0 * inv);
            mp[1] = __float2bfloat16(a1 * inv);
        }
        if (t < 8)
            reinterpret_cast<bf*>(&sA[nrow * 72 + 8])[t] = __float2bfloat16(x[node * DIN + t]);
    }
    __syncthreads();

    int wid = tid >> 6, lane = tid & 63;
    int r16 = lane & 15, k8 = (lane >> 4) * 8;
    bf16x8 av = *reinterpret_cast<const bf16x8*>(&sA[(wid * 16 + r16) * 72 + k8]);
    bf16x8 b0 = *reinterpret_cast<const bf16x8*>(&Bt[r16 * 32 + k8]);
    bf16x8 b1 = *reinterpret_cast<const bf16x8*>(&Bt[(16 + r16) * 32 + k8]);
    f32x4 acc0 = {0.f, 0.f, 0.f, 0.f}, acc1 = {0.f, 0.f, 0.f, 0.f};
    acc0 = __builtin_amdgcn_mfma_f32_16x16x32_bf16(av, b0, acc0, 0, 0, 0);
    acc1 = __builtin_amdgcn_mfma_f32_16x16x32_bf16(av, b1, acc1, 0, 0, 0);
    float bias0 = blv[r16], bias1 = blv[16 + r16];
    int rbase = base + wid * 16 + (lane >> 4) * 4;
#pragma unroll
    for (int reg = 0; reg < 4; ++reg) {
        int node = rbase + reg;
        if (node < NN) {
            hout[node * DH + r16]      = __float2bfloat16(fmaxf(acc0[reg] + bias0, 0.f));
            hout[node * DH + 16 + r16] = __float2bfloat16(fmaxf(acc1[reg] + bias1, 0.f));
        }
    }
}

// ---------------- layer 2: gather-mean(d=32,bf16) -> A[64][72] -> MFMA ----------------
__launch_bounds__(256)
__global__ void layer2_mfma(const bf* __restrict__ hin, const int* __restrict__ degI,
                            const int* __restrict__ start, const int* __restrict__ adj,
                            const u16* __restrict__ Bt, const float* __restrict__ blv,
                            bf* __restrict__ hout) {
    __shared__ short sA[64 * 72];   // [node][k]: k0..31 mean, 32..63 xr
    int tid = threadIdx.x;
    int base = blockIdx.x * 64;

    int g = tid >> 5, t = tid & 31;
    int nb = t >> 3, c4 = t & 7;
    int nbase = base + g * 8;
    for (int i = 0; i < 8; ++i) {
        int node = nbase + i;
        if (node >= NN) break;
        int dg = degI[node];
        int row = start[node];
        float a0 = 0.f, a1 = 0.f, a2 = 0.f, a3 = 0.f;
        for (int idx = nb; idx < dg; idx += 4) {
            int s = adj[row + idx];
            uint2 u = *reinterpret_cast<const uint2*>(&hin[s * DH + c4 * 4]);
            a0 += bflo(u.x); a1 += bfhi(u.x);
            a2 += bflo(u.y); a3 += bfhi(u.y);
        }
        a0 += __shfl_xor(a0, 8);  a1 += __shfl_xor(a1, 8);
        a2 += __shfl_xor(a2, 8);  a3 += __shfl_xor(a3, 8);
        a0 += __shfl_xor(a0, 16); a1 += __shfl_xor(a1, 16);
        a2 += __shfl_xor(a2, 16); a3 += __shfl_xor(a3, 16);
        if (t < 8) {
            float inv = 1.0f / fmaxf((float)dg, 1.0f);
            int nrow = g * 8 + i;
            bf* mp = reinterpret_cast<bf*>(&sA[nrow * 72 + t * 4]);
            mp[0] = __float2bfloat16(a0 * inv);
            mp[1] = __float2bfloat16(a1 * inv);
            mp[2] = __float2bfloat16(a2 * inv);
            mp[3] = __float2bfloat16(a3 * inv);
            *reinterpret_cast<uint2*>(&sA[nrow * 72 + 32 + t * 4]) =
                *reinterpret_cast<const uint2*>(&hin[node * DH + t * 4]);
        }
    }
    __syncthreads();

    int wid = tid >> 6, lane = tid & 63;
    int r16 = lane & 15, k8 = (lane >> 4) * 8;
    const short* ap = &sA[(wid * 16 + r16) * 72];
    bf16x8 av0 = *reinterpret_cast<const bf16x8*>(&ap[k8]);
    bf16x8 av1 = *reinterpret_cast<const bf16x8*>(&ap[32 + k8]);
    const u16* b0p = &Bt[r16 * 64];
    const u16* b1p = &Bt[(16 + r16) * 64];
    bf16x8 b00 = *reinterpret_cast<const bf16x8*>(&b0p[k8]);
    bf16x8 b01 = *reinterpret_cast<const bf16x8*>(&b0p[32 + k8]);
    bf16x8 b10 = *reinterpret_cast<const bf16x8*>(&b1p[k8]);
    bf16x8 b11 = *reinterpret_cast<const bf16x8*>(&b1p[32 + k8]);
    f32x4 acc0 = {0.f, 0.f, 0.f, 0.f}, acc1 = {0.f, 0.f, 0.f, 0.f};
    acc0 = __builtin_amdgcn_mfma_f32_16x16x32_bf16(av0, b00, acc0, 0, 0, 0);
    acc0 = __builtin_amdgcn_mfma_f32_16x16x32_bf16(av1, b01, acc0, 0, 0, 0);
    acc1 = __builtin_amdgcn_mfma_f32_16x16x32_bf16(av0, b10, acc1, 0, 0, 0);
    acc1 = __builtin_amdgcn_mfma_f32_16x16x32_bf16(av1, b11, acc1, 0, 0, 0);
    float bias0 = blv[r16], bias1 = blv[16 + r16];
    int rbase = base + wid * 16 + (lane >> 4) * 4;
#pragma unroll
    for (int reg = 0; reg < 4; ++reg) {
        int node = rbase + reg;
        if (node < NN) {
            hout[node * DH + r16]      = __float2bfloat16(fmaxf(acc0[reg] + bias0, 0.f));
            hout[node * DH + 16 + r16] = __float2bfloat16(fmaxf(acc1[reg] + bias1, 0.f));
        }
    }
}

// ---------------- layer 3 + head: 3 chained MFMA stages ----------------
__launch_bounds__(256)
__global__ void layer3_mfma(const bf* __restrict__ hin, const int* __restrict__ degI,
                            const int* __restrict__ start, const int* __restrict__ adj,
                            const u16* __restrict__ B3t, const float* __restrict__ bl3,
                            const u16* __restrict__ Bh1t, const float* __restrict__ bh1,
                            const float* __restrict__ Wh2, const float* __restrict__ bh2,
                            float* __restrict__ out) {
    __shared__ short sA[64 * 72];    // SAGE input panel
    __shared__ short sA2[64 * 40];   // h3 bf16, padded stride 40
    __shared__ float shm[64 * 36];   // hmid f32, padded stride 36
    __shared__ float sW2[NACT * DH]; // Wh2 transposed [a][k]
    int tid = threadIdx.x;
    int base = blockIdx.x * 64;

    if (tid < NACT * DH) {
        int a = tid >> 5, k = tid & 31;
        sW2[a * DH + k] = Wh2[k * NACT + a];
    }

    int g = tid >> 5, t = tid & 31;
    int nb = t >> 3, c4 = t & 7;
    int nbase = base + g * 8;
    for (int i = 0; i < 8; ++i) {
        int node = nbase + i;
        if (node >= NN) break;
        int dg = degI[node];
        int row = start[node];
        float a0 = 0.f, a1 = 0.f, a2 = 0.f, a3 = 0.f;
        for (int idx = nb; idx < dg; idx += 4) {
            int s = adj[row + idx];
            uint2 u = *reinterpret_cast<const uint2*>(&hin[s * DH + c4 * 4]);
            a0 += bflo(u.x); a1 += bfhi(u.x);
            a2 += bflo(u.y); a3 += bfhi(u.y);
        }
        a0 += __shfl_xor(a0, 8);  a1 += __shfl_xor(a1, 8);
        a2 += __shfl_xor(a2, 8);  a3 += __shfl_xor(a3, 8);
        a0 += __shfl_xor(a0, 16); a1 += __shfl_xor(a1, 16);
        a2 += __shfl_xor(a2, 16); a3 += __shfl_xor(a3, 16);
        if (t < 8) {
            float inv = 1.0f / fmaxf((float)dg, 1.0f);
            int nrow = g * 8 + i;
            bf* mp = reinterpret_cast<bf*>(&sA[nrow * 72 + t * 4]);
            mp[0] = __float2bfloat16(a0 * inv);
            mp[1] = __float2bfloat16(a1 * inv);
            mp[2] = __float2bfloat16(a2 * inv);
            mp[3] = __float2bfloat16(a3 * inv);
            *reinterpret_cast<uint2*>(&sA[nrow * 72 + 32 + t * 4]) =
                *reinterpret_cast<const uint2*>(&hin[node * DH + t * 4]);
        }
    }
    __syncthreads();

    int wid = tid >> 6, lane = tid & 63;
    int r16 = lane & 15, k8 = (lane >> 4) * 8;
    int rloc = wid * 16 + (lane >> 4) * 4;

    {   // stage 1: SAGE conv
        const short* ap = &sA[(wid * 16 + r16) * 72];
        bf16x8 av0 = *reinterpret_cast<const bf16x8*>(&ap[k8]);
        bf16x8 av1 = *reinterpret_cast<const bf16x8*>(&ap[32 + k8]);
        const u16* b0p = &B3t[r16 * 64];
        const u16* b1p = &B3t[(16 + r16) * 64];
        bf16x8 b00 = *reinterpret_cast<const bf16x8*>(&b0p[k8]);
        bf16x8 b01 = *reinterpret_cast<const bf16x8*>(&b0p[32 + k8]);
        bf16x8 b10 = *reinterpret_cast<const bf16x8*>(&b1p[k8]);
        bf16x8 b11 = *reinterpret_cast<const bf16x8*>(&b1p[32 + k8]);
        f32x4 acc0 = {0.f, 0.f, 0.f, 0.f}, acc1 = {0.f, 0.f, 0.f, 0.f};
        acc0 = __builtin_amdgcn_mfma_f32_16x16x32_bf16(av0, b00, acc0, 0, 0, 0);
        acc0 = __builtin_amdgcn_mfma_f32_16x16x32_bf16(av1, b01, acc0, 0, 0, 0);
        acc1 = __builtin_amdgcn_mfma_f32_16x16x32_bf16(av0, b10, acc1, 0, 0, 0);
        acc1 = __builtin_amdgcn_mfma_f32_16x16x32_bf16(av1, b11, acc1, 0, 0, 0);
        float bias0 = bl3[r16], bias1 = bl3[16 + r16];
        bf* a2w = reinterpret_cast<bf*>(sA2);
#pragma unroll
        for (int reg = 0; reg < 4; ++reg) {
            int rr = rloc + reg;
            a2w[rr * 40 + r16]      = __float2bfloat16(fmaxf(acc0[reg] + bias0, 0.f));
            a2w[rr * 40 + 16 + r16] = __float2bfloat16(fmaxf(acc1[reg] + bias1, 0.f));
        }
    }
    __syncthreads();

    {   // stage 2: hmid = relu(h3 @ Wh1 + bh1)
        bf16x8 av = *reinterpret_cast<const bf16x8*>(&sA2[(wid * 16 + r16) * 40 + k8]);
        bf16x8 b0 = *reinterpret_cast<const bf16x8*>(&Bh1t[r16 * 32 + k8]);
        bf16x8 b1 = *reinterpret_cast<const bf16x8*>(&Bh1t[(16 + r16) * 32 + k8]);
        f32x4 d0 = {0.f, 0.f, 0.f, 0.f}, d1 = {0.f, 0.f, 0.f, 0.f};
        d0 = __builtin_amdgcn_mfma_f32_16x16x32_bf16(av, b0, d0, 0, 0, 0);
        d1 = __builtin_amdgcn_mfma_f32_16x16x32_bf16(av, b1, d1, 0, 0, 0);
        float hb0 = bh1[r16], hb1 = bh1[16 + r16];
#pragma unroll
        for (int reg = 0; reg < 4; ++reg) {
            int rr = rloc + reg;
            shm[rr * 36 + r16]      = fmaxf(d0[reg] + hb0, 0.f);
            shm[rr * 36 + 16 + r16] = fmaxf(d1[reg] + hb1, 0.f);
        }
    }
    __syncthreads();

    {   // stage 3: out = hmid @ Wh2 + bh2 (per-thread, 3 cols)
        int m = tid >> 2, a = tid & 3;
        int node = base + m;
        if (a < NACT && node < NN) {
            float o = bh2[a];
            const float* hp = &shm[m * 36];
            const float* wp = &sW2[a * DH];
#pragma unroll
            for (int k = 0; k < DH; k += 4) {
                f32x4 hv = *reinterpret_cast<const f32x4*>(&hp[k]);
                f32x4 wv = *reinterpret_cast<const f32x4*>(&wp[k]);
                o += hv.x * wv.x + hv.y * wv.y + hv.z * wv.z + hv.w * wv.w;
            }
            out[node * NACT + a] = o;
        }
    }
}

extern "C" void kernel_launch(void* const* d_in, const int* in_sizes, int n_in,
                              void* d_out, int out_size, void* d_ws, size_t ws_size,
                              hipStream_t stream) {
    const float* x   = (const float*)d_in[0];
    const int*   ei  = (const int*)d_in[1];
    const int*   src = ei;
    const int*   dst = ei + NE;
    const float* Wl1 = (const float*)d_in[2];
    const float* bl1 = (const float*)d_in[3];
    const float* Wr1 = (const float*)d_in[4];
    const float* Wl2 = (const float*)d_in[5];
    const float* bl2 = (const float*)d_in[6];
    const float* Wr2 = (const float*)d_in[7];
    const float* Wl3 = (const float*)d_in[8];
    const float* bl3 = (const float*)d_in[9];
    const float* Wr3 = (const float*)d_in[10];
    const float* Wh1 = (const float*)d_in[11];
    const float* bh1 = (const float*)d_in[12];
    const float* Wh2 = (const float*)d_in[13];
    const float* bh2 = (const float*)d_in[14];
    float* out = (float*)d_out;

    int* degI   = (int*)d_ws;            // NN
    int* startP = degI + NN;             // NN
    int* cursor = startP + NN;           // NN
    int* bsum   = cursor + NN;           // 512
    int* incl   = bsum + 512;            // PADN
    int* adj    = incl + PADN;           // NE
    u16* B1t    = (u16*)(adj + NE);      // 1024
    u16* B2t    = B1t + 1024;            // 2048
    u16* B3t    = B2t + 2048;            // 2048
    u16* Bh1t   = B3t + 2048;            // 1024
    bf*  hA     = (bf*)(Bh1t + 1024);    // DH*NN
    bf*  hB     = hA + DH * NN;          // DH*NN

    hipMemsetAsync(degI, 0, NN * sizeof(int), stream);

    prep_weights<<<1, 256, 0, stream>>>(Wl1, Wr1, Wl2, Wr2, Wl3, Wr3, Wh1,
                                        B1t, B2t, B3t, Bh1t);

    count_deg_part<<<CHUNKS * 8, 256, 0, stream>>>(dst, degI);
    scanA<<<NBLK, 256, 0, stream>>>(degI, incl, bsum);
    scanB<<<1, 512, 0, stream>>>(bsum);
    scanC<<<NBLK, 256, 0, stream>>>(incl, degI, bsum, startP, cursor);
    fill_csr_part<<<CHUNKS * 8, 256, 0, stream>>>(src, dst, cursor, adj);

    layer1_mfma<<<LGRID, 256, 0, stream>>>(x, degI, startP, adj, B1t, bl1, hA);
    layer2_mfma<<<LGRID, 256, 0, stream>>>(hA, degI, startP, adj, B2t, bl2, hB);
    layer3_mfma<<<LGRID, 256, 0, stream>>>(hB, degI, startP, adj, B3t, bl3,
                                           Bh1t, bh1, Wh2, bh2, out);
}

// Round 8
// 327.137 us; speedup vs baseline: 5.7781x; 1.1466x over previous
//
#include <hip/hip_runtime.h>
#include <hip/hip_bf16.h>

#define NN 100000
#define NE 1600000
#define DIN 8
#define DH 32
#define NACT 3
#define NBLK 391          // ceil(NN/256)
#define PADN (NBLK * 256)
#define NRANGE 12500      // NN / 8
#define CHUNKS 125
#define EC (NE / CHUNKS)  // 12800, multiple of 4
#define LG32 (NN / 32)    // 3125 blocks x 32 nodes (exact)

typedef __hip_bfloat16 bf;
typedef unsigned short u16;
typedef __attribute__((ext_vector_type(8))) short bf16x8;
typedef __attribute__((ext_vector_type(4))) float f32x4;

__device__ __forceinline__ float bflo(unsigned u) { return __uint_as_float(u << 16); }
__device__ __forceinline__ float bfhi(unsigned u) { return __uint_as_float(u & 0xffff0000u); }
__device__ __forceinline__ unsigned pk2(float lo, float hi) {
    union { bf b; unsigned short u; } cl, ch;
    cl.b = __float2bfloat16(lo); ch.b = __float2bfloat16(hi);
    return (unsigned)cl.u | ((unsigned)ch.u << 16);
}

// ---------------- weight prep (bf16 transposed panels) ----------------
__launch_bounds__(256)
__global__ void prep_weights(const float* __restrict__ Wl1, const float* __restrict__ Wr1,
                             const float* __restrict__ Wl2, const float* __restrict__ Wr2,
                             const float* __restrict__ Wl3, const float* __restrict__ Wr3,
                             const float* __restrict__ Wh1,
                             u16* __restrict__ B1t, u16* __restrict__ B2t,
                             u16* __restrict__ B3t, u16* __restrict__ Bh1t) {
    int tid = threadIdx.x;
    for (int idx = tid; idx < 1024; idx += 256) {
        int j = idx >> 5, k = idx & 31;
        float v = (k < 8) ? Wl1[k * DH + j] : ((k < 16) ? Wr1[(k - 8) * DH + j] : 0.0f);
        reinterpret_cast<bf*>(B1t)[j * 32 + k] = __float2bfloat16(v);
    }
    for (int idx = tid; idx < 2048; idx += 256) {
        int j = idx >> 6, k = idx & 63;
        float v = (k < 32) ? Wl2[k * DH + j] : Wr2[(k - 32) * DH + j];
        reinterpret_cast<bf*>(B2t)[j * 64 + k] = __float2bfloat16(v);
    }
    for (int idx = tid; idx < 2048; idx += 256) {
        int j = idx >> 6, k = idx & 63;
        float v = (k < 32) ? Wl3[k * DH + j] : Wr3[(k - 32) * DH + j];
        reinterpret_cast<bf*>(B3t)[j * 64 + k] = __float2bfloat16(v);
    }
    for (int idx = tid; idx < 1024; idx += 256) {
        int j = idx >> 5, k = idx & 31;
        reinterpret_cast<bf*>(Bh1t)[j * 32 + k] = __float2bfloat16(Wh1[k * DH + j]);
    }
}

// ---------------- degree count, XCD-partitioned, int4 reads ----------------
__launch_bounds__(256)
__global__ void count_deg_part(const int* __restrict__ dst, int* __restrict__ degI) {
    int g = blockIdx.x & 7;
    int chunk = blockIdx.x >> 3;
    int lo = g * NRANGE;
    int e0 = chunk * EC;
    for (int e = e0 + (int)threadIdx.x * 4; e < e0 + EC; e += 1024) {
        int4 d4 = *reinterpret_cast<const int4*>(&dst[e]);
        if ((unsigned)(d4.x - lo) < (unsigned)NRANGE) atomicAdd(&degI[d4.x], 1);
        if ((unsigned)(d4.y - lo) < (unsigned)NRANGE) atomicAdd(&degI[d4.y], 1);
        if ((unsigned)(d4.z - lo) < (unsigned)NRANGE) atomicAdd(&degI[d4.z], 1);
        if ((unsigned)(d4.w - lo) < (unsigned)NRANGE) atomicAdd(&degI[d4.w], 1);
    }
}

// ---------------- scan A/B/C ----------------
__launch_bounds__(256)
__global__ void scanA(const int* __restrict__ degI, int* __restrict__ incl,
                      int* __restrict__ bsum) {
    __shared__ int s[256];
    int i = blockIdx.x * 256 + threadIdx.x;
    int v = (i < NN) ? degI[i] : 0;
    s[threadIdx.x] = v;
    __syncthreads();
#pragma unroll
    for (int off = 1; off < 256; off <<= 1) {
        int t = (threadIdx.x >= off) ? s[threadIdx.x - off] : 0;
        __syncthreads();
        s[threadIdx.x] += t;
        __syncthreads();
    }
    incl[i] = s[threadIdx.x];
    if (threadIdx.x == 255) bsum[blockIdx.x] = s[255];
}

__launch_bounds__(512)
__global__ void scanB(int* __restrict__ bsum) {
    __shared__ int s[512];
    int tid = threadIdx.x;
    int v = (tid < NBLK) ? bsum[tid] : 0;
    s[tid] = v;
    __syncthreads();
#pragma unroll
    for (int off = 1; off < 512; off <<= 1) {
        int t = (tid >= off) ? s[tid - off] : 0;
        __syncthreads();
        s[tid] += t;
        __syncthreads();
    }
    if (tid < NBLK) bsum[tid] = s[tid] - v;
}

__launch_bounds__(256)
__global__ void scanC(const int* __restrict__ incl, const int* __restrict__ degI,
                      const int* __restrict__ bsum, int* __restrict__ start,
                      int* __restrict__ cursor) {
    int i = blockIdx.x * 256 + threadIdx.x;
    if (i < NN) {
        int st = incl[i] - degI[i] + bsum[blockIdx.x];
        start[i] = st;
        cursor[i] = st;
    }
}

// ---------------- CSR fill, XCD-partitioned, int4 reads ----------------
__launch_bounds__(256)
__global__ void fill_csr_part(const int* __restrict__ src, const int* __restrict__ dst,
                              int* __restrict__ cursor, int* __restrict__ adj) {
    int g = blockIdx.x & 7;
    int chunk = blockIdx.x >> 3;
    int lo = g * NRANGE;
    int e0 = chunk * EC;
    for (int e = e0 + (int)threadIdx.x * 4; e < e0 + EC; e += 1024) {
        int4 d4 = *reinterpret_cast<const int4*>(&dst[e]);
        int4 s4 = *reinterpret_cast<const int4*>(&src[e]);
        if ((unsigned)(d4.x - lo) < (unsigned)NRANGE) adj[atomicAdd(&cursor[d4.x], 1)] = s4.x;
        if ((unsigned)(d4.y - lo) < (unsigned)NRANGE) adj[atomicAdd(&cursor[d4.y], 1)] = s4.y;
        if ((unsigned)(d4.z - lo) < (unsigned)NRANGE) adj[atomicAdd(&cursor[d4.z], 1)] = s4.z;
        if ((unsigned)(d4.w - lo) < (unsigned)NRANGE) adj[atomicAdd(&cursor[d4.w], 1)] = s4.w;
    }
}

// ============ layer 1: uniform-shfl gather(d=8,f32) -> A[32][72] -> MFMA ============
// 128 threads = 4 groups x 32 lanes; 8 nodes/group.
__launch_bounds__(128)
__global__ void layer1_mfma(const float* __restrict__ x, const int* __restrict__ degI,
                            const int* __restrict__ start, const int* __restrict__ adj,
                            const u16* __restrict__ Bt, const float* __restrict__ blv,
                            bf* __restrict__ hout) {
    __shared__ __align__(16) short sA[32 * 72];
    int tid = threadIdx.x;
    int base = blockIdx.x * 32;

    {   // zero pad k=16..31 region
        int row = tid >> 2, part = tid & 3;
        *reinterpret_cast<uint2*>(&sA[row * 72 + 16 + part * 4]) = make_uint2(0u, 0u);
    }

    int g = tid >> 5, t = tid & 31;
    int nb = t >> 1, q = t & 1;    // 16 neighbor slots x 2 half-rows(16B)
    int nbase = base + g * 8;
    int dgv = 0, stv = 0;
    if (t < 8) { dgv = degI[nbase + t]; stv = start[nbase + t]; }

#pragma unroll 4
    for (int i = 0; i < 8; ++i) {
        int dg  = __shfl(dgv, i, 32);
        int row = __shfl(stv, i, 32);
        int node = nbase + i;
        int idxreg = (t < dg) ? adj[row + t] : 0;
        float4 xv;
        if (t == 2 || t == 3)
            xv = *reinterpret_cast<const float4*>(&x[node * DIN + (t - 2) * 4]);
        float a[4] = {0.f, 0.f, 0.f, 0.f};
        int lim = min(dg, 32);
        int nit = (lim + 15) >> 4;   // uniform trip count: ALL lanes run the shfl
        for (int j = 0; j < nit; ++j) {
            int k = nb + j * 16;
            int s = __shfl(idxreg, k, 32);   // all lanes active -> defined
            float4 v = *reinterpret_cast<const float4*>(&x[s * DIN + q * 4]);
            if (k < lim) { a[0] += v.x; a[1] += v.y; a[2] += v.z; a[3] += v.w; }
        }
        for (int k = 32 + nb; k < dg; k += 16) {   // rare deg>32 tail (direct loads)
            int s = adj[row + k];
            float4 v = *reinterpret_cast<const float4*>(&x[s * DIN + q * 4]);
            a[0] += v.x; a[1] += v.y; a[2] += v.z; a[3] += v.w;
        }
#pragma unroll
        for (int m = 0; m < 4; ++m) {
            a[m] += __shfl_xor(a[m], 2);
            a[m] += __shfl_xor(a[m], 4);
            a[m] += __shfl_xor(a[m], 8);
            a[m] += __shfl_xor(a[m], 16);
        }
        int nrow = g * 8 + i;
        if (t < 2) {
            float inv = 1.0f / fmaxf((float)dg, 1.0f);
            uint2 mm;
            mm.x = pk2(a[0] * inv, a[1] * inv);
            mm.y = pk2(a[2] * inv, a[3] * inv);
            *reinterpret_cast<uint2*>(&sA[nrow * 72 + t * 4]) = mm;
        } else if (t < 4) {
            uint2 xm;
            xm.x = pk2(xv.x, xv.y);
            xm.y = pk2(xv.z, xv.w);
            *reinterpret_cast<uint2*>(&sA[nrow * 72 + 8 + (t - 2) * 4]) = xm;
        }
    }
    __syncthreads();

    int wid = tid >> 6, lane = tid & 63;
    int r16 = lane & 15, k8 = (lane >> 4) * 8;
    bf16x8 av = *reinterpret_cast<const bf16x8*>(&sA[(wid * 16 + r16) * 72 + k8]);
    bf16x8 b0 = *reinterpret_cast<const bf16x8*>(&Bt[r16 * 32 + k8]);
    bf16x8 b1 = *reinterpret_cast<const bf16x8*>(&Bt[(16 + r16) * 32 + k8]);
    f32x4 acc0 = {0.f, 0.f, 0.f, 0.f}, acc1 = {0.f, 0.f, 0.f, 0.f};
    acc0 = __builtin_amdgcn_mfma_f32_16x16x32_bf16(av, b0, acc0, 0, 0, 0);
    acc1 = __builtin_amdgcn_mfma_f32_16x16x32_bf16(av, b1, acc1, 0, 0, 0);
    float bias0 = blv[r16], bias1 = blv[16 + r16];
    int rbase = base + wid * 16 + (lane >> 4) * 4;
#pragma unroll
    for (int reg = 0; reg < 4; ++reg) {
        int node = rbase + reg;
        hout[node * DH + r16]      = __float2bfloat16(fmaxf(acc0[reg] + bias0, 0.f));
        hout[node * DH + 16 + r16] = __float2bfloat16(fmaxf(acc1[reg] + bias1, 0.f));
    }
}

// ============ shared gather for d=32 bf16 panels (uniform shfl loop) ============
__device__ __forceinline__ void gather32(const bf* __restrict__ hin,
                                         const int* __restrict__ degI,
                                         const int* __restrict__ start,
                                         const int* __restrict__ adj,
                                         short* sA, int base, int tid) {
    int g = tid >> 5, t = tid & 31;
    int nb = t >> 2, q = t & 3;    // 8 neighbor slots x 4 quarters(16B)
    int nbase = base + g * 8;
    int dgv = 0, stv = 0;
    if (t < 8) { dgv = degI[nbase + t]; stv = start[nbase + t]; }

#pragma unroll 4
    for (int i = 0; i < 8; ++i) {
        int dg  = __shfl(dgv, i, 32);
        int row = __shfl(stv, i, 32);
        int node = nbase + i;
        int idxreg = (t < dg) ? adj[row + t] : 0;
        uint4 xru;
        if ((t & 28) == 4)   // t in 4..7: own-row copy
            xru = *reinterpret_cast<const uint4*>(&hin[node * DH + (t - 4) * 8]);
        float a[8] = {0.f, 0.f, 0.f, 0.f, 0.f, 0.f, 0.f, 0.f};
        int lim = min(dg, 32);
        int nit = (lim + 7) >> 3;    // uniform: ALL lanes run each shfl
        for (int j = 0; j < nit; ++j) {
            int k = nb + j * 8;      // k <= 7+24 = 31
            int s = __shfl(idxreg, k, 32);   // all lanes active -> defined
            uint4 u = *reinterpret_cast<const uint4*>(&hin[s * DH + q * 8]);
            if (k < lim) {
                a[0] += bflo(u.x); a[1] += bfhi(u.x);
                a[2] += bflo(u.y); a[3] += bfhi(u.y);
                a[4] += bflo(u.z); a[5] += bfhi(u.z);
                a[6] += bflo(u.w); a[7] += bfhi(u.w);
            }
        }
        for (int k = 32 + nb; k < dg; k += 8) {   // rare deg>32 tail (direct loads)
            int s = adj[row + k];
            uint4 u = *reinterpret_cast<const uint4*>(&hin[s * DH + q * 8]);
            a[0] += bflo(u.x); a[1] += bfhi(u.x);
            a[2] += bflo(u.y); a[3] += bfhi(u.y);
            a[4] += bflo(u.z); a[5] += bfhi(u.z);
            a[6] += bflo(u.w); a[7] += bfhi(u.w);
        }
#pragma unroll
        for (int m = 0; m < 8; ++m) {
            a[m] += __shfl_xor(a[m], 4);
            a[m] += __shfl_xor(a[m], 8);
            a[m] += __shfl_xor(a[m], 16);
        }
        int nrow = g * 8 + i;
        if (t < 4) {
            float inv = 1.0f / fmaxf((float)dg, 1.0f);
            uint4 mm;
            mm.x = pk2(a[0] * inv, a[1] * inv);
            mm.y = pk2(a[2] * inv, a[3] * inv);
            mm.z = pk2(a[4] * inv, a[5] * inv);
            mm.w = pk2(a[6] * inv, a[7] * inv);
            *reinterpret_cast<uint4*>(&sA[nrow * 72 + t * 8]) = mm;
        } else if (t < 8) {
            *reinterpret_cast<uint4*>(&sA[nrow * 72 + 32 + (t - 4) * 8]) = xru;
        }
    }
}

// ============ layer 2 ============
__launch_bounds__(128)
__global__ void layer2_mfma(const bf* __restrict__ hin, const int* __restrict__ degI,
                            const int* __restrict__ start, const int* __restrict__ adj,
                            const u16* __restrict__ Bt, const float* __restrict__ blv,
                            bf* __restrict__ hout) {
    __shared__ __align__(16) short sA[32 * 72];
    int tid = threadIdx.x;
    int base = blockIdx.x * 32;

    gather32(hin, degI, start, adj, sA, base, tid);
    __syncthreads();

    int wid = tid >> 6, lane = tid & 63;
    int r16 = lane & 15, k8 = (lane >> 4) * 8;
    const short* ap = &sA[(wid * 16 + r16) * 72];
    bf16x8 av0 = *reinterpret_cast<const bf16x8*>(&ap[k8]);
    bf16x8 av1 = *reinterpret_cast<const bf16x8*>(&ap[32 + k8]);
    const u16* b0p = &Bt[r16 * 64];
    const u16* b1p = &Bt[(16 + r16) * 64];
    bf16x8 b00 = *reinterpret_cast<const bf16x8*>(&b0p[k8]);
    bf16x8 b01 = *reinterpret_cast<const bf16x8*>(&b0p[32 + k8]);
    bf16x8 b10 = *reinterpret_cast<const bf16x8*>(&b1p[k8]);
    bf16x8 b11 = *reinterpret_cast<const bf16x8*>(&b1p[32 + k8]);
    f32x4 acc0 = {0.f, 0.f, 0.f, 0.f}, acc1 = {0.f, 0.f, 0.f, 0.f};
    acc0 = __builtin_amdgcn_mfma_f32_16x16x32_bf16(av0, b00, acc0, 0, 0, 0);
    acc0 = __builtin_amdgcn_mfma_f32_16x16x32_bf16(av1, b01, acc0, 0, 0, 0);
    acc1 = __builtin_amdgcn_mfma_f32_16x16x32_bf16(av0, b10, acc1, 0, 0, 0);
    acc1 = __builtin_amdgcn_mfma_f32_16x16x32_bf16(av1, b11, acc1, 0, 0, 0);
    float bias0 = blv[r16], bias1 = blv[16 + r16];
    int rbase = base + wid * 16 + (lane >> 4) * 4;
#pragma unroll
    for (int reg = 0; reg < 4; ++reg) {
        int node = rbase + reg;
        hout[node * DH + r16]      = __float2bfloat16(fmaxf(acc0[reg] + bias0, 0.f));
        hout[node * DH + 16 + r16] = __float2bfloat16(fmaxf(acc1[reg] + bias1, 0.f));
    }
}

// ============ layer 3 + head (LDS overlaid: sA -> h3 -> hmid) ============
__launch_bounds__(128)
__global__ void layer3_mfma(const bf* __restrict__ hin, const int* __restrict__ degI,
                            const int* __restrict__ start, const int* __restrict__ adj,
                            const u16* __restrict__ B3t, const float* __restrict__ bl3,
                            const u16* __restrict__ Bh1t, const float* __restrict__ bh1,
                            const float* __restrict__ Wh2, const float* __restrict__ bh2,
                            float* __restrict__ out) {
    __shared__ __align__(16) short sA[32 * 72];
    __shared__ float sW2[NACT * DH];
    int tid = threadIdx.x;
    int base = blockIdx.x * 32;

    if (tid < NACT * DH) {
        int a = tid >> 5, k = tid & 31;
        sW2[a * DH + k] = Wh2[k * NACT + a];
    }

    gather32(hin, degI, start, adj, sA, base, tid);
    __syncthreads();

    int wid = tid >> 6, lane = tid & 63;
    int r16 = lane & 15, k8 = (lane >> 4) * 8;
    int rloc = wid * 16 + (lane >> 4) * 4;

    // stage 1: SAGE conv
    f32x4 acc0 = {0.f, 0.f, 0.f, 0.f}, acc1 = {0.f, 0.f, 0.f, 0.f};
    {
        const short* ap = &sA[(wid * 16 + r16) * 72];
        bf16x8 av0 = *reinterpret_cast<const bf16x8*>(&ap[k8]);
        bf16x8 av1 = *reinterpret_cast<const bf16x8*>(&ap[32 + k8]);
        const u16* b0p = &B3t[r16 * 64];
        const u16* b1p = &B3t[(16 + r16) * 64];
        bf16x8 b00 = *reinterpret_cast<const bf16x8*>(&b0p[k8]);
        bf16x8 b01 = *reinterpret_cast<const bf16x8*>(&b0p[32 + k8]);
        bf16x8 b10 = *reinterpret_cast<const bf16x8*>(&b1p[k8]);
        bf16x8 b11 = *reinterpret_cast<const bf16x8*>(&b1p[32 + k8]);
        acc0 = __builtin_amdgcn_mfma_f32_16x16x32_bf16(av0, b00, acc0, 0, 0, 0);
        acc0 = __builtin_amdgcn_mfma_f32_16x16x32_bf16(av1, b01, acc0, 0, 0, 0);
        acc1 = __builtin_amdgcn_mfma_f32_16x16x32_bf16(av0, b10, acc1, 0, 0, 0);
        acc1 = __builtin_amdgcn_mfma_f32_16x16x32_bf16(av1, b11, acc1, 0, 0, 0);
    }
    __syncthreads();   // all sA reads landed in regs

    bf* h3b = reinterpret_cast<bf*>(sA);   // overlay: [32][40] bf16
    {
        float bias0 = bl3[r16], bias1 = bl3[16 + r16];
#pragma unroll
        for (int reg = 0; reg < 4; ++reg) {
            int rr = rloc + reg;
            h3b[rr * 40 + r16]      = __float2bfloat16(fmaxf(acc0[reg] + bias0, 0.f));
            h3b[rr * 40 + 16 + r16] = __float2bfloat16(fmaxf(acc1[reg] + bias1, 0.f));
        }
    }
    __syncthreads();   // h3 ready

    // stage 2: hmid = relu(h3 @ Wh1 + bh1)
    f32x4 d0 = {0.f, 0.f, 0.f, 0.f}, d1 = {0.f, 0.f, 0.f, 0.f};
    {
        bf16x8 av = *reinterpret_cast<const bf16x8*>(&h3b[(wid * 16 + r16) * 40 + k8]);
        bf16x8 b0 = *reinterpret_cast<const bf16x8*>(&Bh1t[r16 * 32 + k8]);
        bf16x8 b1 = *reinterpret_cast<const bf16x8*>(&Bh1t[(16 + r16) * 32 + k8]);
        d0 = __builtin_amdgcn_mfma_f32_16x16x32_bf16(av, b0, d0, 0, 0, 0);
        d1 = __builtin_amdgcn_mfma_f32_16x16x32_bf16(av, b1, d1, 0, 0, 0);
    }
    __syncthreads();   // h3 reads done

    float* shm = reinterpret_cast<float*>(sA);   // overlay: [32][36] f32
    {
        float hb0 = bh1[r16], hb1 = bh1[16 + r16];
#pragma unroll
        for (int reg = 0; reg < 4; ++reg) {
            int rr = rloc + reg;
            shm[rr * 36 + r16]      = fmaxf(d0[reg] + hb0, 0.f);
            shm[rr * 36 + 16 + r16] = fmaxf(d1[reg] + hb1, 0.f);
        }
    }
    __syncthreads();   // hmid ready

    // stage 3: out = hmid @ Wh2 + bh2
    {
        int m = tid >> 2, a = tid & 3;
        if (a < NACT) {
            float o = bh2[a];
            const float* hp = &shm[m * 36];
            const float* wp = &sW2[a * DH];
#pragma unroll
            for (int k = 0; k < DH; k += 4) {
                f32x4 hv = *reinterpret_cast<const f32x4*>(&hp[k]);
                f32x4 wv = *reinterpret_cast<const f32x4*>(&wp[k]);
                o += hv.x * wv.x + hv.y * wv.y + hv.z * wv.z + hv.w * wv.w;
            }
            out[(base + m) * NACT + a] = o;
        }
    }
}

extern "C" void kernel_launch(void* const* d_in, const int* in_sizes, int n_in,
                              void* d_out, int out_size, void* d_ws, size_t ws_size,
                              hipStream_t stream) {
    const float* x   = (const float*)d_in[0];
    const int*   ei  = (const int*)d_in[1];
    const int*   src = ei;
    const int*   dst = ei + NE;
    const float* Wl1 = (const float*)d_in[2];
    const float* bl1 = (const float*)d_in[3];
    const float* Wr1 = (const float*)d_in[4];
    const float* Wl2 = (const float*)d_in[5];
    const float* bl2 = (const float*)d_in[6];
    const float* Wr2 = (const float*)d_in[7];
    const float* Wl3 = (const float*)d_in[8];
    const float* bl3 = (const float*)d_in[9];
    const float* Wr3 = (const float*)d_in[10];
    const float* Wh1 = (const float*)d_in[11];
    const float* bh1 = (const float*)d_in[12];
    const float* Wh2 = (const float*)d_in[13];
    const float* bh2 = (const float*)d_in[14];
    float* out = (float*)d_out;

    int* degI   = (int*)d_ws;            // NN
    int* startP = degI + NN;             // NN
    int* cursor = startP + NN;           // NN
    int* bsum   = cursor + NN;           // 512
    int* incl   = bsum + 512;            // PADN
    int* adj    = incl + PADN;           // NE
    u16* B1t    = (u16*)(adj + NE);      // 1024
    u16* B2t    = B1t + 1024;            // 2048
    u16* B3t    = B2t + 2048;            // 2048
    u16* Bh1t   = B3t + 2048;            // 1024
    bf*  hA     = (bf*)(Bh1t + 1024);    // DH*NN
    bf*  hB     = hA + DH * NN;          // DH*NN

    hipMemsetAsync(degI, 0, NN * sizeof(int), stream);

    prep_weights<<<1, 256, 0, stream>>>(Wl1, Wr1, Wl2, Wr2, Wl3, Wr3, Wh1,
                                        B1t, B2t, B3t, Bh1t);

    count_deg_part<<<CHUNKS * 8, 256, 0, stream>>>(dst, degI);
    scanA<<<NBLK, 256, 0, stream>>>(degI, incl, bsum);
    scanB<<<1, 512, 0, stream>>>(bsum);
    scanC<<<NBLK, 256, 0, stream>>>(incl, degI, bsum, startP, cursor);
    fill_csr_part<<<CHUNKS * 8, 256, 0, stream>>>(src, dst, cursor, adj);

    layer1_mfma<<<LG32, 128, 0, stream>>>(x, degI, startP, adj, B1t, bl1, hA);
    layer2_mfma<<<LG32, 128, 0, stream>>>(hA, degI, startP, adj, B2t, bl2, hB);
    layer3_mfma<<<LG32, 128, 0, stream>>>(hB, degI, startP, adj, B3t, bl3,
                                          Bh1t, bh1, Wh2, bh2, out);
}